// Round 2
// baseline (41877.353 us; speedup 1.0000x reference)
//
#include <hip/hip_runtime.h>
#include <hip/hip_bf16.h>
#include <hip/hip_fp16.h>

// Problem sizes
#define NB 32
#define NT 256
#define NH 256
#define NV 32000
#define NL2 512     // fixed KV length = 2T
#define NTP1 257    // T+1

typedef unsigned int u32x4 __attribute__((ext_vector_type(4)));
typedef short s16x8 __attribute__((ext_vector_type(8)));
typedef float f32x4 __attribute__((ext_vector_type(4)));

__device__ __forceinline__ float fast_tanh(float x) {
  x = fminf(15.f, fmaxf(-15.f, x));
  float e = __expf(2.f * x);
  return 1.f - __fdividef(2.f, e + 1.f);
}
__device__ __forceinline__ float fast_sigmoid(float x) {
  x = fminf(30.f, fmaxf(-30.f, x));
  float e = __expf(-x);
  return __fdividef(1.f, 1.f + e);
}
__device__ __forceinline__ unsigned short f2bf(float f) {  // RNE fp32->bf16
  unsigned int u = __builtin_bit_cast(unsigned int, f);
  return (unsigned short)((u + 0x7FFFu + ((u >> 16) & 1u)) >> 16);
}
__device__ __forceinline__ float dot4(f32x4 a, f32x4 b, float acc) {
  acc = fmaf(a.x, b.x, acc);
  acc = fmaf(a.y, b.y, acc);
  acc = fmaf(a.z, b.z, acc);
  acc = fmaf(a.w, b.w, acc);
  return acc;
}

// ---------------- setup kernels ----------------

__global__ void conv_bf16_kernel(const float* __restrict__ s, unsigned short* __restrict__ d, int n) {
  int i = blockIdx.x * 256 + threadIdx.x;
  if (i < n) d[i] = f2bf(s[i]);
}

// enc_proj_w (256,512) -> wT (512,256)
__global__ void transpose_kernel(const float* __restrict__ w, float* __restrict__ wT) {
  int i = blockIdx.x * 256 + threadIdx.x;
  if (i < 256 * 512) { int h = i >> 9, dd = i & 511; wT[dd * 256 + h] = w[i]; }
}

// proj[b,s,h] = enc_proj_b[h] + sum_d enc[s,b,d]*W[h,d]; write kvT[b][h][s] (f32)
__global__ __launch_bounds__(256) void proj_kernel(const float* __restrict__ enc,
                                                   const float* __restrict__ wT,
                                                   const float* __restrict__ pb,
                                                   float* __restrict__ kvT) {
  int gid = blockIdx.x * 256 + threadIdx.x;
  int h4 = gid & 63;
  int bs = gid >> 6;                 // = s*32 + b (matches enc layout)
  if (bs >= NTP1 * NB) return;
  int s = bs >> 5, b = bs & 31;
  const float* er = enc + (size_t)bs * 512;
  float a0 = 0.f, a1 = 0.f, a2 = 0.f, a3 = 0.f;
  for (int d = 0; d < 512; d += 4) {
    f32x4 e4 = *(const f32x4*)(er + d);
    f32x4 w0 = *(const f32x4*)(wT + (size_t)(d + 0) * 256 + h4 * 4);
    f32x4 w1 = *(const f32x4*)(wT + (size_t)(d + 1) * 256 + h4 * 4);
    f32x4 w2 = *(const f32x4*)(wT + (size_t)(d + 2) * 256 + h4 * 4);
    f32x4 w3 = *(const f32x4*)(wT + (size_t)(d + 3) * 256 + h4 * 4);
    a0 = fmaf(e4.x, w0.x, a0); a1 = fmaf(e4.x, w0.y, a1); a2 = fmaf(e4.x, w0.z, a2); a3 = fmaf(e4.x, w0.w, a3);
    a0 = fmaf(e4.y, w1.x, a0); a1 = fmaf(e4.y, w1.y, a1); a2 = fmaf(e4.y, w1.z, a2); a3 = fmaf(e4.y, w1.w, a3);
    a0 = fmaf(e4.z, w2.x, a0); a1 = fmaf(e4.z, w2.y, a1); a2 = fmaf(e4.z, w2.z, a2); a3 = fmaf(e4.z, w2.w, a3);
    a0 = fmaf(e4.w, w3.x, a0); a1 = fmaf(e4.w, w3.y, a1); a2 = fmaf(e4.w, w3.z, a2); a3 = fmaf(e4.w, w3.w, a3);
  }
  int h = h4 * 4;
  a0 += pb[h + 0]; a1 += pb[h + 1]; a2 += pb[h + 2]; a3 += pb[h + 3];
  size_t base = ((size_t)b * NH) * NL2 + s;
  kvT[base + (size_t)(h + 0) * NL2] = a0;
  kvT[base + (size_t)(h + 1) * NL2] = a1;
  kvT[base + (size_t)(h + 2) * NL2] = a2;
  kvT[base + (size_t)(h + 3) * NL2] = a3;
}

// kprojT[b][g][l] = sum_h kvT[b][h][l] * wk[g][h], for l < 257
__global__ __launch_bounds__(256) void kproj0_kernel(const float* __restrict__ kvT,
                                                     const float* __restrict__ wk,
                                                     float* __restrict__ kprojT) {
  int b = blockIdx.x >> 3, gq = blockIdx.x & 7;
  __shared__ float wks[32][256];
  __shared__ float pk[32][8];
  int tid = threadIdx.x;
  for (int i = tid; i < 32 * 256; i += 256) {
    int g = i >> 8, h = i & 255;
    wks[g][h] = wk[(size_t)(gq * 32 + g) * 256 + h];
  }
  __syncthreads();
  {
    int l = tid;   // l in [0,256)
    float acc[32];
#pragma unroll
    for (int g = 0; g < 32; ++g) acc[g] = 0.f;
    for (int h = 0; h < 256; ++h) {
      float kvv = kvT[((size_t)(b * NH + h)) * NL2 + l];
#pragma unroll
      for (int g = 0; g < 32; ++g) acc[g] = fmaf(kvv, wks[g][h], acc[g]);
    }
    for (int g = 0; g < 32; ++g)
      kprojT[((size_t)(b * NH + gq * 32 + g)) * NL2 + l] = acc[g];
  }
  // l == 256 handled cooperatively
  {
    int g = tid >> 3, hc = tid & 7;
    float acc = 0.f;
    for (int h = hc * 32; h < hc * 32 + 32; ++h)
      acc += kvT[((size_t)(b * NH + h)) * NL2 + 256] * wks[g][h];
    pk[g][hc] = acc;
    __syncthreads();
    if (tid < 32) {
      float sv = 0.f;
      for (int c = 0; c < 8; ++c) sv += pk[tid][c];
      kprojT[((size_t)(b * NH + gq * 32 + tid)) * NL2 + 256] = sv;
    }
  }
}

// ---------------- the sequential scan: one workgroup per batch, full fp32 ----------------

__global__ __launch_bounds__(1024) void scan_kernel(
    const int* __restrict__ x, const float* __restrict__ efs, const float* __restrict__ emb,
    const float* __restrict__ wq, const float* __restrict__ wk, const float* __restrict__ wv,
    const float* __restrict__ wih0, const float* __restrict__ whh0,
    const float* __restrict__ bih0, const float* __restrict__ bhh0,
    const float* __restrict__ wih1, const float* __restrict__ whh1,
    const float* __restrict__ bih1, const float* __restrict__ bhh1,
    float* __restrict__ kvT, float* __restrict__ kprojT,
    unsigned short* __restrict__ outs_bf, float* __restrict__ attn_out) {
  __shared__ __align__(16) float h0s[256], h1s[256], qf[256];
  __shared__ __align__(16) float sc[512], attns[512], sp[2][512];
  __shared__ __align__(16) float ctxp[4][256], xins[512];
  __shared__ __align__(16) float gi[768], gh[768], wvs[256], red[32];

  int tid = threadIdx.x;
  int b = blockIdx.x;

  if (tid < 256) {
    h0s[tid] = efs[(size_t)(0 * NB + b) * NH + tid] + efs[(size_t)(1 * NB + b) * NH + tid];
    h1s[tid] = efs[(size_t)(2 * NB + b) * NH + tid] + efs[(size_t)(3 * NB + b) * NH + tid];
    wvs[tid] = wv[tid];
  }
  __syncthreads();

  for (int t = 0; t < NT; ++t) {
    int Lt = NTP1 + t;
    // -- phase 1: emb gather (into xins high half) + q = h1 @ wq^T
    if (tid < 256) {
      int tok = x[b * NT + t];
      xins[256 + tid] = emb[(size_t)tok * 256 + tid];
      const float* wr = wq + (size_t)tid * 256;
      float acc = 0.f;
      for (int k = 0; k < 256; k += 4)
        acc = dot4(*(const f32x4*)(wr + k), *(const f32x4*)(h1s + k), acc);
      qf[tid] = acc;
    }
    __syncthreads();
    // -- phase 2: scores (lane = l, wave splits g in halves of 128)
    {
      int w = tid >> 6, lane = tid & 63;
      int wsub = w & 7, gsub = w >> 3;
      int l = wsub * 64 + lane;
      float acc = 0.f;
      if (l < Lt) {
        int gbase = gsub * 128;
        const float* kp = kprojT + ((size_t)(b * NH + gbase)) * NL2 + l;
        for (int g = 0; g < 128; g += 4) {
          f32x4 q4 = *(const f32x4*)(qf + gbase + g);
          f32x4 w4 = *(const f32x4*)(wvs + gbase + g);
          float k0 = kp[0];
          float k1 = kp[512];
          float k2 = kp[1024];
          float k3 = kp[1536];
          kp += 2048;
          acc = fmaf(w4.x, fast_tanh(k0 + q4.x), acc);
          acc = fmaf(w4.y, fast_tanh(k1 + q4.y), acc);
          acc = fmaf(w4.z, fast_tanh(k2 + q4.z), acc);
          acc = fmaf(w4.w, fast_tanh(k3 + q4.w), acc);
        }
      }
      sp[gsub][l] = acc;
    }
    __syncthreads();
    // -- phase 3: combine + max reduce (xor butterfly: defined on all lanes)
    {
      float v = (tid < 512 && tid < Lt) ? (sp[0][tid] + sp[1][tid]) : -3.0e38f;
      if (tid < 512) sc[tid] = v;
      for (int off = 32; off; off >>= 1) v = fmaxf(v, __shfl_xor(v, off, 64));
      if ((tid & 63) == 0) red[tid >> 6] = v;
    }
    __syncthreads();
    if (tid == 0) {
      float m = red[0];
      for (int i = 1; i < 16; ++i) m = fmaxf(m, red[i]);
      red[16] = m;
    }
    __syncthreads();
    {
      float M = red[16];
      float e = 0.f;
      if (tid < 512) {
        e = (tid < Lt) ? __expf(sc[tid] - M) : 0.f;
        sc[tid] = e;
      }
      float v = e;
      for (int off = 32; off; off >>= 1) v += __shfl_xor(v, off, 64);
      if ((tid & 63) == 0) red[tid >> 6] = v;
    }
    __syncthreads();
    if (tid == 0) {
      float z = 0.f;
      for (int i = 0; i < 16; ++i) z += red[i];
      red[17] = z;
    }
    __syncthreads();
    {
      float Z = red[17];
      if (tid < 512) {
        float a = __fdividef(sc[tid], Z);            // exact 0 for invalid slots
        attn_out[((size_t)(b * NT + t)) * NL2 + tid] = a;
        attns[tid] = a;
      }
    }
    __syncthreads();
    // -- phase 4: context = attn @ kv  (invalid slots: attn==0, kv zero-inited)
    {
      int h = tid & 255, qq = tid >> 8;
      const float* kvr = kvT + ((size_t)(b * NH + h)) * NL2 + qq * 128;
      const float* ar = attns + qq * 128;
      float acc = 0.f;
      for (int k = 0; k < 128; k += 4)
        acc = dot4(*(const f32x4*)(ar + k), *(const f32x4*)(kvr + k), acc);
      ctxp[qq][h] = acc;
    }
    __syncthreads();
    if (tid < 256) xins[tid] = ctxp[0][tid] + ctxp[1][tid] + ctxp[2][tid] + ctxp[3][tid];
    __syncthreads();
    // -- phase 5: GRU layer 0 matvecs
    if (tid < 768) {
      const float* wi = wih0 + (size_t)tid * 512;
      float ai = bih0[tid];
      for (int k = 0; k < 512; k += 4)
        ai = dot4(*(const f32x4*)(wi + k), *(const f32x4*)(xins + k), ai);
      const float* wh = whh0 + (size_t)tid * 256;
      float ah = bhh0[tid];
      for (int k = 0; k < 256; k += 4)
        ah = dot4(*(const f32x4*)(wh + k), *(const f32x4*)(h0s + k), ah);
      gi[tid] = ai; gh[tid] = ah;
    }
    __syncthreads();
    if (tid < 256) {
      float r = fast_sigmoid(gi[tid] + gh[tid]);
      float z = fast_sigmoid(gi[256 + tid] + gh[256 + tid]);
      float n = fast_tanh(gi[512 + tid] + r * gh[512 + tid]);
      h0s[tid] = (1.f - z) * n + z * h0s[tid];
    }
    __syncthreads();
    // -- phase 6: GRU layer 1 matvecs (input = new h0, state = old h1)
    if (tid < 768) {
      const float* wi = wih1 + (size_t)tid * 256;
      float ai = bih1[tid];
      for (int k = 0; k < 256; k += 4)
        ai = dot4(*(const f32x4*)(wi + k), *(const f32x4*)(h0s + k), ai);
      const float* wh = whh1 + (size_t)tid * 256;
      float ah = bhh1[tid];
      for (int k = 0; k < 256; k += 4)
        ah = dot4(*(const f32x4*)(wh + k), *(const f32x4*)(h1s + k), ah);
      gi[tid] = ai; gh[tid] = ah;
    }
    __syncthreads();
    if (tid < 256) {
      float r = fast_sigmoid(gi[tid] + gh[tid]);
      float z = fast_sigmoid(gi[256 + tid] + gh[256 + tid]);
      float n = fast_tanh(gi[512 + tid] + r * gh[512 + tid]);
      float hn = (1.f - z) * n + z * h1s[tid];
      h1s[tid] = hn;
      outs_bf[((size_t)(b * NT + t)) * NH + tid] = f2bf(hn);
    }
    __syncthreads();
    // -- phase 7: append kv/kproj row at pos = 257+t (skip final step)
    if (t < NT - 1 && tid < 256) {
      int pos = NTP1 + t;
      kvT[((size_t)(b * NH + tid)) * NL2 + pos] = h1s[tid];
      const float* wr = wk + (size_t)tid * 256;
      float acc = 0.f;
      for (int k = 0; k < 256; k += 4)
        acc = dot4(*(const f32x4*)(wr + k), *(const f32x4*)(h1s + k), acc);
      kprojT[((size_t)(b * NH + tid)) * NL2 + pos] = acc;
    }
    __syncthreads();
  }
}

// ---------------- logits GEMM: C(8192x32000) = A(8192x256) * B^T + bias, bf16 MFMA ----------------

__global__ __launch_bounds__(256) void logits_gemm(const unsigned short* __restrict__ A,
                                                   const unsigned short* __restrict__ Bw,
                                                   const float* __restrict__ bias,
                                                   float* __restrict__ C) {
  __shared__ unsigned short As[128][88];
  __shared__ unsigned short Bs[128][88];
  int tid = threadIdx.x;
  int nt = blockIdx.x % 250, mt = blockIdx.x / 250;
  int m0 = mt * 128, n0 = nt * 128;
  int lane = tid & 63, w = tid >> 6;
  int wm = w & 1, wn = w >> 1;
  f32x4 acc[4][4];
#pragma unroll
  for (int m = 0; m < 4; ++m)
#pragma unroll
    for (int n = 0; n < 4; ++n) acc[m][n] = (f32x4)0.0f;

  int r0 = tid >> 3;
  int c0 = (tid & 7) * 8;
  for (int kt = 0; kt < 4; ++kt) {
    __syncthreads();
#pragma unroll
    for (int it = 0; it < 4; ++it) {
      int row = it * 32 + r0;
      u32x4 va = *(const u32x4*)(A + (size_t)(m0 + row) * 256 + kt * 64 + c0);
      u32x4 vb = *(const u32x4*)(Bw + (size_t)(n0 + row) * 256 + kt * 64 + c0);
      *(u32x4*)(&As[row][c0]) = va;
      *(u32x4*)(&Bs[row][c0]) = vb;
    }
    __syncthreads();
#pragma unroll
    for (int ks = 0; ks < 2; ++ks) {
      s16x8 af[4], bf[4];
#pragma unroll
      for (int m = 0; m < 4; ++m)
        af[m] = *(const s16x8*)(&As[wm * 64 + m * 16 + (lane & 15)][ks * 32 + (lane >> 4) * 8]);
#pragma unroll
      for (int n = 0; n < 4; ++n)
        bf[n] = *(const s16x8*)(&Bs[wn * 64 + n * 16 + (lane & 15)][ks * 32 + (lane >> 4) * 8]);
#pragma unroll
      for (int m = 0; m < 4; ++m)
#pragma unroll
        for (int n = 0; n < 4; ++n)
          acc[m][n] = __builtin_amdgcn_mfma_f32_16x16x32_bf16(af[m], bf[n], acc[m][n], 0, 0, 0);
    }
  }
#pragma unroll
  for (int n = 0; n < 4; ++n) {
    int col = n0 + wn * 64 + n * 16 + (lane & 15);
    float bv = bias[col];
#pragma unroll
    for (int m = 0; m < 4; ++m) {
      int rowb = m0 + wm * 64 + m * 16 + (lane >> 4) * 4;
#pragma unroll
      for (int r = 0; r < 4; ++r)
        C[(size_t)(rowb + r) * NV + col] = acc[m][n][r] + bv;
    }
  }
}

// ---------------- host launch ----------------

extern "C" void kernel_launch(void* const* d_in, const int* in_sizes, int n_in,
                              void* d_out, int out_size, void* d_ws, size_t ws_size,
                              hipStream_t stream) {
  const int*   x    = (const int*)d_in[0];
  const float* enc  = (const float*)d_in[1];
  const float* efs  = (const float*)d_in[2];
  const float* emb  = (const float*)d_in[3];
  const float* epw  = (const float*)d_in[4];
  const float* epb  = (const float*)d_in[5];
  const float* wq   = (const float*)d_in[6];
  const float* wk   = (const float*)d_in[7];
  const float* wv   = (const float*)d_in[8];
  const float* wih0 = (const float*)d_in[9];
  const float* whh0 = (const float*)d_in[10];
  const float* bih0 = (const float*)d_in[11];
  const float* bhh0 = (const float*)d_in[12];
  const float* wih1 = (const float*)d_in[13];
  const float* whh1 = (const float*)d_in[14];
  const float* bih1 = (const float*)d_in[15];
  const float* bhh1 = (const float*)d_in[16];
  const float* dw   = (const float*)d_in[17];
  const float* db   = (const float*)d_in[18];

  // workspace layout (bytes)
  const size_t o_dwbf   = 0;                        // 16,384,000
  const size_t o_wT     = o_dwbf + 16384000;        // 524,288
  const size_t o_kvT    = o_wT + 524288;            // 16,777,216 (f32)
  const size_t o_kproj  = o_kvT + 16777216;         // 16,777,216 (f32)
  const size_t o_outs   = o_kproj + 16777216;       // 4,194,304 (bf16)
  const size_t need     = o_outs + 4194304;         // ~54.7 MB
  if (ws_size < need) return;  // fail visibly rather than corrupt

  char* ws = (char*)d_ws;
  unsigned short* dwbf16 = (unsigned short*)(ws + o_dwbf);
  float* wT          = (float*)(ws + o_wT);
  float* kvT         = (float*)(ws + o_kvT);
  float* kprojT      = (float*)(ws + o_kproj);
  unsigned short* outs_bf = (unsigned short*)(ws + o_outs);

  float* logits = (float*)d_out;
  float* attn_out = logits + (size_t)NB * NT * NV;

  // zero-init KV buffers (invalid slots must be finite; first run ws is undefined)
  hipMemsetAsync(ws + o_kvT, 0, 2 * 16777216, stream);

  // conversions
  conv_bf16_kernel<<<(8192000 + 255) / 256, 256, 0, stream>>>(dw, dwbf16, 8192000);
  transpose_kernel<<<(131072 + 255) / 256, 256, 0, stream>>>(epw, wT);

  // encoder projection -> kvT, then key projections -> kprojT
  proj_kernel<<<(NTP1 * NB * 64) / 256, 256, 0, stream>>>(enc, wT, epb, kvT);
  kproj0_kernel<<<NB * 8, 256, 0, stream>>>(kvT, wk, kprojT);

  // sequential scan: one workgroup per batch, full fp32
  scan_kernel<<<NB, 1024, 0, stream>>>(x, efs, emb, wq, wk, wv,
                                       wih0, whh0, bih0, bhh0,
                                       wih1, whh1, bih1, bhh1,
                                       kvT, kprojT, outs_bf, attn_out);

  // final big GEMM: logits
  logits_gemm<<<(NB * NT / 128) * (NV / 128), 256, 0, stream>>>(outs_bf, dwbf16, db, logits);
}

// Round 3
// 24700.668 us; speedup vs baseline: 1.6954x; 1.6954x over previous
//
#include <hip/hip_runtime.h>
#include <hip/hip_bf16.h>
#include <hip/hip_fp16.h>

// Problem sizes
#define NB 32
#define NT 256
#define NH 256
#define NV 32000
#define NL2 512     // fixed KV length = 2T
#define NTP1 257    // T+1

typedef unsigned int u32x4 __attribute__((ext_vector_type(4)));
typedef short s16x8 __attribute__((ext_vector_type(8)));
typedef float f32x4 __attribute__((ext_vector_type(4)));
typedef _Float16 half2v __attribute__((ext_vector_type(2)));

__device__ __forceinline__ float dot2f(half2v a, half2v b, float c) {
#if __has_builtin(__builtin_amdgcn_fdot2)
  return __builtin_amdgcn_fdot2(a, b, c, false);
#else
  return c + (float)a[0] * (float)b[0] + (float)a[1] * (float)b[1];
#endif
}
__device__ __forceinline__ half2v h2(unsigned int u) { return __builtin_bit_cast(half2v, u); }

// f16 dot: w global (b128 loads), x LDS. n multiple of 16. fp32 accumulate.
__device__ __forceinline__ float dotf16(const _Float16* __restrict__ w,
                                        const _Float16* __restrict__ x, int n, float acc) {
#pragma unroll 4
  for (int k = 0; k < n; k += 16) {
    u32x4 a0 = *(const u32x4*)(w + k);
    u32x4 a1 = *(const u32x4*)(w + k + 8);
    u32x4 b0 = *(const u32x4*)(x + k);
    u32x4 b1 = *(const u32x4*)(x + k + 8);
    acc = dot2f(h2(a0.x), h2(b0.x), acc);
    acc = dot2f(h2(a0.y), h2(b0.y), acc);
    acc = dot2f(h2(a0.z), h2(b0.z), acc);
    acc = dot2f(h2(a0.w), h2(b0.w), acc);
    acc = dot2f(h2(a1.x), h2(b1.x), acc);
    acc = dot2f(h2(a1.y), h2(b1.y), acc);
    acc = dot2f(h2(a1.z), h2(b1.z), acc);
    acc = dot2f(h2(a1.w), h2(b1.w), acc);
  }
  return acc;
}

__device__ __forceinline__ float fast_tanh(float x) {
  x = fminf(15.f, fmaxf(-15.f, x));
  float e = __expf(2.f * x);
  return 1.f - __fdividef(2.f, e + 1.f);
}
__device__ __forceinline__ float fast_sigmoid(float x) {
  x = fminf(30.f, fmaxf(-30.f, x));
  float e = __expf(-x);
  return __fdividef(1.f, 1.f + e);
}
__device__ __forceinline__ unsigned short f2bf(float f) {  // RNE fp32->bf16
  unsigned int u = __builtin_bit_cast(unsigned int, f);
  return (unsigned short)((u + 0x7FFFu + ((u >> 16) & 1u)) >> 16);
}
__device__ __forceinline__ float dot4(f32x4 a, f32x4 b, float acc) {
  acc = fmaf(a.x, b.x, acc);
  acc = fmaf(a.y, b.y, acc);
  acc = fmaf(a.z, b.z, acc);
  acc = fmaf(a.w, b.w, acc);
  return acc;
}

// ---------------- setup kernels ----------------

__global__ void conv_f16_kernel(const float* __restrict__ s, _Float16* __restrict__ d, int n) {
  int i = blockIdx.x * 256 + threadIdx.x;
  if (i < n) d[i] = (_Float16)s[i];
}

__global__ void conv_bf16_kernel(const float* __restrict__ s, unsigned short* __restrict__ d, int n) {
  int i = blockIdx.x * 256 + threadIdx.x;
  if (i < n) d[i] = f2bf(s[i]);
}

// enc_proj_w (256,512) -> wT (512,256)
__global__ void transpose_kernel(const float* __restrict__ w, float* __restrict__ wT) {
  int i = blockIdx.x * 256 + threadIdx.x;
  if (i < 256 * 512) { int h = i >> 9, dd = i & 511; wT[dd * 256 + h] = w[i]; }
}

// proj[b,s,h] = enc_proj_b[h] + sum_d enc[s,b,d]*W[h,d]; write kvT[b][h][s] (f32)
__global__ __launch_bounds__(256) void proj_kernel(const float* __restrict__ enc,
                                                   const float* __restrict__ wT,
                                                   const float* __restrict__ pb,
                                                   float* __restrict__ kvT) {
  int gid = blockIdx.x * 256 + threadIdx.x;
  int h4 = gid & 63;
  int bs = gid >> 6;                 // = s*32 + b (matches enc layout)
  if (bs >= NTP1 * NB) return;
  int s = bs >> 5, b = bs & 31;
  const float* er = enc + (size_t)bs * 512;
  float a0 = 0.f, a1 = 0.f, a2 = 0.f, a3 = 0.f;
  for (int d = 0; d < 512; d += 4) {
    f32x4 e4 = *(const f32x4*)(er + d);
    f32x4 w0 = *(const f32x4*)(wT + (size_t)(d + 0) * 256 + h4 * 4);
    f32x4 w1 = *(const f32x4*)(wT + (size_t)(d + 1) * 256 + h4 * 4);
    f32x4 w2 = *(const f32x4*)(wT + (size_t)(d + 2) * 256 + h4 * 4);
    f32x4 w3 = *(const f32x4*)(wT + (size_t)(d + 3) * 256 + h4 * 4);
    a0 = fmaf(e4.x, w0.x, a0); a1 = fmaf(e4.x, w0.y, a1); a2 = fmaf(e4.x, w0.z, a2); a3 = fmaf(e4.x, w0.w, a3);
    a0 = fmaf(e4.y, w1.x, a0); a1 = fmaf(e4.y, w1.y, a1); a2 = fmaf(e4.y, w1.z, a2); a3 = fmaf(e4.y, w1.w, a3);
    a0 = fmaf(e4.z, w2.x, a0); a1 = fmaf(e4.z, w2.y, a1); a2 = fmaf(e4.z, w2.z, a2); a3 = fmaf(e4.z, w2.w, a3);
    a0 = fmaf(e4.w, w3.x, a0); a1 = fmaf(e4.w, w3.y, a1); a2 = fmaf(e4.w, w3.z, a2); a3 = fmaf(e4.w, w3.w, a3);
  }
  int h = h4 * 4;
  a0 += pb[h + 0]; a1 += pb[h + 1]; a2 += pb[h + 2]; a3 += pb[h + 3];
  size_t base = ((size_t)b * NH) * NL2 + s;
  kvT[base + (size_t)(h + 0) * NL2] = a0;
  kvT[base + (size_t)(h + 1) * NL2] = a1;
  kvT[base + (size_t)(h + 2) * NL2] = a2;
  kvT[base + (size_t)(h + 3) * NL2] = a3;
}

// kprojL[b][l][g] = sum_h kvT[b][h][l] * wk[g][h], for l < 257
__global__ __launch_bounds__(256) void kproj0_kernel(const float* __restrict__ kvT,
                                                     const float* __restrict__ wk,
                                                     float* __restrict__ kprojL) {
  int b = blockIdx.x >> 3, gq = blockIdx.x & 7;
  __shared__ float wks[32][256];
  __shared__ float pk[32][8];
  int tid = threadIdx.x;
  for (int i = tid; i < 32 * 256; i += 256) {
    int g = i >> 8, h = i & 255;
    wks[g][h] = wk[(size_t)(gq * 32 + g) * 256 + h];
  }
  __syncthreads();
  {
    int l = tid;   // l in [0,256)
    float acc[32];
#pragma unroll
    for (int g = 0; g < 32; ++g) acc[g] = 0.f;
    for (int h = 0; h < 256; ++h) {
      float kvv = kvT[((size_t)(b * NH + h)) * NL2 + l];
#pragma unroll
      for (int g = 0; g < 32; ++g) acc[g] = fmaf(kvv, wks[g][h], acc[g]);
    }
    for (int g = 0; g < 32; ++g)
      kprojL[((size_t)b * NL2 + l) * NH + gq * 32 + g] = acc[g];
  }
  // l == 256 handled cooperatively
  {
    int g = tid >> 3, hc = tid & 7;
    float acc = 0.f;
    for (int h = hc * 32; h < hc * 32 + 32; ++h)
      acc += kvT[((size_t)(b * NH + h)) * NL2 + 256] * wks[g][h];
    pk[g][hc] = acc;
    __syncthreads();
    if (tid < 32) {
      float sv = 0.f;
      for (int c = 0; c < 8; ++c) sv += pk[tid][c];
      kprojL[((size_t)b * NL2 + 256) * NH + gq * 32 + tid] = sv;
    }
  }
}

// ---------------- sequential scan: one WG per batch; f16 weights, fp32 state ----------------

__global__ __launch_bounds__(1024) void scan_kernel(
    const int* __restrict__ x, const float* __restrict__ efs, const float* __restrict__ emb,
    const float* __restrict__ wv,
    const float* __restrict__ bih0, const float* __restrict__ bhh0,
    const float* __restrict__ bih1, const float* __restrict__ bhh1,
    const _Float16* __restrict__ wq16, const _Float16* __restrict__ wk16,
    const _Float16* __restrict__ wih0_16, const _Float16* __restrict__ whh0_16,
    const _Float16* __restrict__ wih1_16, const _Float16* __restrict__ whh1_16,
    float* __restrict__ kvT, float* __restrict__ kprojL,
    unsigned short* __restrict__ outs_bf, float* __restrict__ attn_out) {
  __shared__ __align__(16) float h0s[256], h1s[256], qf[256];
  __shared__ __align__(16) float sc[512], attns[512], sp[2][512];
  __shared__ __align__(16) float ctxp[4][256];
  __shared__ __align__(16) float gi[768], gh[768], wvs[256], red[32];
  __shared__ __align__(16) _Float16 h0h[256], h1h[256], xin16[512];

  int tid = threadIdx.x;
  int b = blockIdx.x;

  if (tid < 256) {
    float h0v = efs[(size_t)(0 * NB + b) * NH + tid] + efs[(size_t)(1 * NB + b) * NH + tid];
    float h1v = efs[(size_t)(2 * NB + b) * NH + tid] + efs[(size_t)(3 * NB + b) * NH + tid];
    h0s[tid] = h0v; h0h[tid] = (_Float16)h0v;
    h1s[tid] = h1v; h1h[tid] = (_Float16)h1v;
    wvs[tid] = wv[tid];
  }
  __syncthreads();

  for (int t = 0; t < NT; ++t) {
    int Lt = NTP1 + t;
    // -- phase 1: emb gather + q = h1 @ wq^T (f16 weights, fp32 acc)
    if (tid < 256) {
      int tok = x[b * NT + t];
      xin16[256 + tid] = (_Float16)emb[(size_t)tok * 256 + tid];
      qf[tid] = dotf16(wq16 + (size_t)tid * 256, h1h, 256, 0.f);
    }
    __syncthreads();
    // -- phase 2: scores; kproj rows are g-contiguous -> f32x4 streams
    {
      int half = tid >> 9, l = tid & 511;
      float acc = 0.f;
      if (l < Lt) {
        const float* kp = kprojL + ((size_t)b * NL2 + l) * NH + half * 128;
        const float* qh = qf + half * 128;
        const float* wh = wvs + half * 128;
#pragma unroll 4
        for (int g = 0; g < 128; g += 4) {
          f32x4 k4 = *(const f32x4*)(kp + g);
          f32x4 q4 = *(const f32x4*)(qh + g);
          f32x4 w4 = *(const f32x4*)(wh + g);
          acc = fmaf(w4.x, fast_tanh(k4.x + q4.x), acc);
          acc = fmaf(w4.y, fast_tanh(k4.y + q4.y), acc);
          acc = fmaf(w4.z, fast_tanh(k4.z + q4.z), acc);
          acc = fmaf(w4.w, fast_tanh(k4.w + q4.w), acc);
        }
      }
      sp[half][l] = acc;
    }
    __syncthreads();
    // -- phase 3: combine + softmax (xor butterfly reductions)
    {
      float v = (tid < 512 && tid < Lt) ? (sp[0][tid] + sp[1][tid]) : -3.0e38f;
      if (tid < 512) sc[tid] = v;
      for (int off = 32; off; off >>= 1) v = fmaxf(v, __shfl_xor(v, off, 64));
      if ((tid & 63) == 0) red[tid >> 6] = v;
    }
    __syncthreads();
    if (tid == 0) {
      float m = red[0];
      for (int i = 1; i < 16; ++i) m = fmaxf(m, red[i]);
      red[16] = m;
    }
    __syncthreads();
    {
      float M = red[16];
      float e = 0.f;
      if (tid < 512) {
        e = (tid < Lt) ? __expf(sc[tid] - M) : 0.f;
        sc[tid] = e;
      }
      float v = e;
      for (int off = 32; off; off >>= 1) v += __shfl_xor(v, off, 64);
      if ((tid & 63) == 0) red[tid >> 6] = v;
    }
    __syncthreads();
    if (tid == 0) {
      float z = 0.f;
      for (int i = 0; i < 16; ++i) z += red[i];
      red[17] = z;
    }
    __syncthreads();
    {
      float Z = red[17];
      if (tid < 512) {
        float a = __fdividef(sc[tid], Z);            // exact 0 for invalid slots
        attn_out[((size_t)(b * NT + t)) * NL2 + tid] = a;
        attns[tid] = a;
      }
    }
    __syncthreads();
    // -- phase 4: context = attn @ kv (fp32), bounded by Lt
    {
      int h = tid & 255, qq = tid >> 8;
      int base = qq * 128;
      int len = Lt - base; len = len < 0 ? 0 : (len > 128 ? 128 : len);
      len = (len + 3) & ~3;                          // attn==0 padding is safe
      const float* kvr = kvT + ((size_t)(b * NH + h)) * NL2 + base;
      const float* ar = attns + base;
      float acc = 0.f;
#pragma unroll 4
      for (int k = 0; k < len; k += 4)
        acc = dot4(*(const f32x4*)(ar + k), *(const f32x4*)(kvr + k), acc);
      ctxp[qq][h] = acc;
    }
    __syncthreads();
    if (tid < 256)
      xin16[tid] = (_Float16)(ctxp[0][tid] + ctxp[1][tid] + ctxp[2][tid] + ctxp[3][tid]);
    __syncthreads();
    // -- phase 5: GRU layer 0 (f16 weights/activations, fp32 gates+state)
    if (tid < 768) {
      gi[tid] = dotf16(wih0_16 + (size_t)tid * 512, xin16, 512, bih0[tid]);
      gh[tid] = dotf16(whh0_16 + (size_t)tid * 256, h0h, 256, bhh0[tid]);
    }
    __syncthreads();
    if (tid < 256) {
      float r = fast_sigmoid(gi[tid] + gh[tid]);
      float z = fast_sigmoid(gi[256 + tid] + gh[256 + tid]);
      float n = fast_tanh(gi[512 + tid] + r * gh[512 + tid]);
      float hn = (1.f - z) * n + z * h0s[tid];
      h0s[tid] = hn; h0h[tid] = (_Float16)hn;
    }
    __syncthreads();
    // -- phase 6: GRU layer 1
    if (tid < 768) {
      gi[tid] = dotf16(wih1_16 + (size_t)tid * 256, h0h, 256, bih1[tid]);
      gh[tid] = dotf16(whh1_16 + (size_t)tid * 256, h1h, 256, bhh1[tid]);
    }
    __syncthreads();
    if (tid < 256) {
      float r = fast_sigmoid(gi[tid] + gh[tid]);
      float z = fast_sigmoid(gi[256 + tid] + gh[256 + tid]);
      float n = fast_tanh(gi[512 + tid] + r * gh[512 + tid]);
      float hn = (1.f - z) * n + z * h1s[tid];
      h1s[tid] = hn; h1h[tid] = (_Float16)hn;
      outs_bf[((size_t)(b * NT + t)) * NH + tid] = f2bf(hn);
    }
    __syncthreads();
    // -- phase 7: append kv column + kproj row at pos = 257+t
    if (t < NT - 1 && tid < 256) {
      int pos = NTP1 + t;
      kvT[((size_t)(b * NH + tid)) * NL2 + pos] = h1s[tid];
      kprojL[((size_t)b * NL2 + pos) * NH + tid] =
          dotf16(wk16 + (size_t)tid * 256, h1h, 256, 0.f);
    }
    __syncthreads();
  }
}

// ---------------- logits GEMM: C(8192x32000) = A(8192x256) * B^T + bias, bf16 MFMA ----------------

__global__ __launch_bounds__(256) void logits_gemm(const unsigned short* __restrict__ A,
                                                   const unsigned short* __restrict__ Bw,
                                                   const float* __restrict__ bias,
                                                   float* __restrict__ C) {
  __shared__ unsigned short As[128][88];
  __shared__ unsigned short Bs[128][88];
  int tid = threadIdx.x;
  int nt = blockIdx.x % 250, mt = blockIdx.x / 250;
  int m0 = mt * 128, n0 = nt * 128;
  int lane = tid & 63, w = tid >> 6;
  int wm = w & 1, wn = w >> 1;
  f32x4 acc[4][4];
#pragma unroll
  for (int m = 0; m < 4; ++m)
#pragma unroll
    for (int n = 0; n < 4; ++n) acc[m][n] = (f32x4)0.0f;

  int r0 = tid >> 3;
  int c0 = (tid & 7) * 8;
  for (int kt = 0; kt < 4; ++kt) {
    __syncthreads();
#pragma unroll
    for (int it = 0; it < 4; ++it) {
      int row = it * 32 + r0;
      u32x4 va = *(const u32x4*)(A + (size_t)(m0 + row) * 256 + kt * 64 + c0);
      u32x4 vb = *(const u32x4*)(Bw + (size_t)(n0 + row) * 256 + kt * 64 + c0);
      *(u32x4*)(&As[row][c0]) = va;
      *(u32x4*)(&Bs[row][c0]) = vb;
    }
    __syncthreads();
#pragma unroll
    for (int ks = 0; ks < 2; ++ks) {
      s16x8 af[4], bf[4];
#pragma unroll
      for (int m = 0; m < 4; ++m)
        af[m] = *(const s16x8*)(&As[wm * 64 + m * 16 + (lane & 15)][ks * 32 + (lane >> 4) * 8]);
#pragma unroll
      for (int n = 0; n < 4; ++n)
        bf[n] = *(const s16x8*)(&Bs[wn * 64 + n * 16 + (lane & 15)][ks * 32 + (lane >> 4) * 8]);
#pragma unroll
      for (int m = 0; m < 4; ++m)
#pragma unroll
        for (int n = 0; n < 4; ++n)
          acc[m][n] = __builtin_amdgcn_mfma_f32_16x16x32_bf16(af[m], bf[n], acc[m][n], 0, 0, 0);
    }
  }
#pragma unroll
  for (int n = 0; n < 4; ++n) {
    int col = n0 + wn * 64 + n * 16 + (lane & 15);
    float bv = bias[col];
#pragma unroll
    for (int m = 0; m < 4; ++m) {
      int rowb = m0 + wm * 64 + m * 16 + (lane >> 4) * 4;
#pragma unroll
      for (int r = 0; r < 4; ++r)
        C[(size_t)(rowb + r) * NV + col] = acc[m][n][r] + bv;
    }
  }
}

// ---------------- host launch ----------------

extern "C" void kernel_launch(void* const* d_in, const int* in_sizes, int n_in,
                              void* d_out, int out_size, void* d_ws, size_t ws_size,
                              hipStream_t stream) {
  const int*   x    = (const int*)d_in[0];
  const float* enc  = (const float*)d_in[1];
  const float* efs  = (const float*)d_in[2];
  const float* emb  = (const float*)d_in[3];
  const float* epw  = (const float*)d_in[4];
  const float* epb  = (const float*)d_in[5];
  const float* wq   = (const float*)d_in[6];
  const float* wk   = (const float*)d_in[7];
  const float* wv   = (const float*)d_in[8];
  const float* wih0 = (const float*)d_in[9];
  const float* whh0 = (const float*)d_in[10];
  const float* bih0 = (const float*)d_in[11];
  const float* bhh0 = (const float*)d_in[12];
  const float* wih1 = (const float*)d_in[13];
  const float* whh1 = (const float*)d_in[14];
  const float* bih1 = (const float*)d_in[15];
  const float* bhh1 = (const float*)d_in[16];
  const float* dw   = (const float*)d_in[17];
  const float* db   = (const float*)d_in[18];

  // workspace layout (bytes) — same 54.7 MB footprint as R2:
  // f16 weights alias the dwbf16 region (scan uses them; conv_bf16 runs AFTER scan)
  const size_t o_dwbf   = 0;                        // 16,384,000
  const size_t o_wT     = o_dwbf + 16384000;        // 524,288
  const size_t o_kvT    = o_wT + 524288;            // 16,777,216 (f32)
  const size_t o_kproj  = o_kvT + 16777216;         // 16,777,216 (f32)
  const size_t o_outs   = o_kproj + 16777216;       // 4,194,304 (bf16)
  const size_t need     = o_outs + 4194304;         // ~54.7 MB
  if (ws_size < need) return;  // fail visibly rather than corrupt

  char* ws = (char*)d_ws;
  unsigned short* dwbf16 = (unsigned short*)(ws + o_dwbf);
  // f16 weight block lives inside [o_dwbf, o_dwbf+2.23MB) until the scan is done
  _Float16* wq16    = (_Float16*)(ws + o_dwbf);            // 131,072 B
  _Float16* wk16    = (_Float16*)(ws + o_dwbf + 131072);   // 131,072 B
  _Float16* wih0_16 = (_Float16*)(ws + o_dwbf + 262144);   // 786,432 B
  _Float16* whh0_16 = (_Float16*)(ws + o_dwbf + 1048576);  // 393,216 B
  _Float16* wih1_16 = (_Float16*)(ws + o_dwbf + 1441792);  // 393,216 B
  _Float16* whh1_16 = (_Float16*)(ws + o_dwbf + 1835008);  // 393,216 B
  float* wT          = (float*)(ws + o_wT);
  float* kvT         = (float*)(ws + o_kvT);
  float* kprojL      = (float*)(ws + o_kproj);
  unsigned short* outs_bf = (unsigned short*)(ws + o_outs);

  float* logits = (float*)d_out;
  float* attn_out = logits + (size_t)NB * NT * NV;

  // zero-init KV buffers (invalid slots must be finite)
  hipMemsetAsync(ws + o_kvT, 0, 2 * 16777216, stream);

  // f16 weight conversions (into the region later overwritten by dwbf16)
  conv_f16_kernel<<<(65536 + 255) / 256, 256, 0, stream>>>(wq, wq16, 65536);
  conv_f16_kernel<<<(65536 + 255) / 256, 256, 0, stream>>>(wk, wk16, 65536);
  conv_f16_kernel<<<(393216 + 255) / 256, 256, 0, stream>>>(wih0, wih0_16, 393216);
  conv_f16_kernel<<<(196608 + 255) / 256, 256, 0, stream>>>(whh0, whh0_16, 196608);
  conv_f16_kernel<<<(196608 + 255) / 256, 256, 0, stream>>>(wih1, wih1_16, 196608);
  conv_f16_kernel<<<(196608 + 255) / 256, 256, 0, stream>>>(whh1, whh1_16, 196608);
  transpose_kernel<<<(131072 + 255) / 256, 256, 0, stream>>>(epw, wT);

  // encoder projection -> kvT, then key projections -> kprojL [b][l][g]
  proj_kernel<<<(NTP1 * NB * 64) / 256, 256, 0, stream>>>(enc, wT, epb, kvT);
  kproj0_kernel<<<NB * 8, 256, 0, stream>>>(kvT, wk, kprojL);

  // sequential scan: one workgroup per batch
  scan_kernel<<<NB, 1024, 0, stream>>>(x, efs, emb, wv, bih0, bhh0, bih1, bhh1,
                                       wq16, wk16, wih0_16, whh0_16, wih1_16, whh1_16,
                                       kvT, kprojL, outs_bf, attn_out);

  // now safe to overwrite the f16-weight region with bf16 dense_w
  conv_bf16_kernel<<<(8192000 + 255) / 256, 256, 0, stream>>>(dw, dwbf16, 8192000);

  // final big GEMM: logits
  logits_gemm<<<(NB * NT / 128) * (NV / 128), 256, 0, stream>>>(outs_bf, dwbf16, db, logits);
}

// Round 4
// 23294.473 us; speedup vs baseline: 1.7977x; 1.0604x over previous
//
#include <hip/hip_runtime.h>
#include <hip/hip_bf16.h>
#include <hip/hip_fp16.h>

// Problem sizes
#define NB 32
#define NT 256
#define NH 256
#define NV 32000
#define NL2 512     // fixed KV length = 2T
#define NTP1 257    // T+1

typedef unsigned int u32x4 __attribute__((ext_vector_type(4)));
typedef short s16x8 __attribute__((ext_vector_type(8)));
typedef float f32x4 __attribute__((ext_vector_type(4)));
typedef _Float16 half2v __attribute__((ext_vector_type(2)));

__device__ __forceinline__ float dot2f(half2v a, half2v b, float c) {
#if __has_builtin(__builtin_amdgcn_fdot2)
  return __builtin_amdgcn_fdot2(a, b, c, false);
#else
  return c + (float)a[0] * (float)b[0] + (float)a[1] * (float)b[1];
#endif
}
__device__ __forceinline__ half2v h2(unsigned int u) { return __builtin_bit_cast(half2v, u); }

// f16 dot: w global (b128 loads), x LDS. n multiple of 16. fp32 accumulate.
__device__ __forceinline__ float dotf16(const _Float16* __restrict__ w,
                                        const _Float16* __restrict__ x, int n, float acc) {
#pragma unroll 8
  for (int k = 0; k < n; k += 16) {
    u32x4 a0 = *(const u32x4*)(w + k);
    u32x4 a1 = *(const u32x4*)(w + k + 8);
    u32x4 b0 = *(const u32x4*)(x + k);
    u32x4 b1 = *(const u32x4*)(x + k + 8);
    acc = dot2f(h2(a0.x), h2(b0.x), acc);
    acc = dot2f(h2(a0.y), h2(b0.y), acc);
    acc = dot2f(h2(a0.z), h2(b0.z), acc);
    acc = dot2f(h2(a0.w), h2(b0.w), acc);
    acc = dot2f(h2(a1.x), h2(b1.x), acc);
    acc = dot2f(h2(a1.y), h2(b1.y), acc);
    acc = dot2f(h2(a1.z), h2(b1.z), acc);
    acc = dot2f(h2(a1.w), h2(b1.w), acc);
  }
  return acc;
}

__device__ __forceinline__ float fast_tanh(float x) {
  x = fminf(15.f, fmaxf(-15.f, x));
  float e = __expf(2.f * x);
  return 1.f - __fdividef(2.f, e + 1.f);
}
__device__ __forceinline__ float fast_sigmoid(float x) {
  x = fminf(30.f, fmaxf(-30.f, x));
  float e = __expf(-x);
  return __fdividef(1.f, 1.f + e);
}
__device__ __forceinline__ unsigned short f2bf(float f) {  // RNE fp32->bf16
  unsigned int u = __builtin_bit_cast(unsigned int, f);
  return (unsigned short)((u + 0x7FFFu + ((u >> 16) & 1u)) >> 16);
}
__device__ __forceinline__ float dot4(f32x4 a, f32x4 b, float acc) {
  acc = fmaf(a.x, b.x, acc);
  acc = fmaf(a.y, b.y, acc);
  acc = fmaf(a.z, b.z, acc);
  acc = fmaf(a.w, b.w, acc);
  return acc;
}

// ---------------- setup kernels ----------------

__global__ void conv_f16_kernel(const float* __restrict__ s, _Float16* __restrict__ d, int n) {
  int i = blockIdx.x * 256 + threadIdx.x;
  if (i < n) d[i] = (_Float16)s[i];
}

__global__ void conv_bf16_kernel(const float* __restrict__ s, unsigned short* __restrict__ d, int n) {
  int i = blockIdx.x * 256 + threadIdx.x;
  if (i < n) d[i] = f2bf(s[i]);
}

// enc_proj_w (256,512) -> wT (512,256)
__global__ void transpose_kernel(const float* __restrict__ w, float* __restrict__ wT) {
  int i = blockIdx.x * 256 + threadIdx.x;
  if (i < 256 * 512) { int h = i >> 9, dd = i & 511; wT[dd * 256 + h] = w[i]; }
}

// proj[b,s,h] = enc_proj_b[h] + sum_d enc[s,b,d]*W[h,d]; write kvT[b][h][s] (f16)
__global__ __launch_bounds__(256) void proj_kernel(const float* __restrict__ enc,
                                                   const float* __restrict__ wT,
                                                   const float* __restrict__ pb,
                                                   _Float16* __restrict__ kvT) {
  int gid = blockIdx.x * 256 + threadIdx.x;
  int h4 = gid & 63;
  int bs = gid >> 6;                 // = s*32 + b (matches enc layout)
  if (bs >= NTP1 * NB) return;
  int s = bs >> 5, b = bs & 31;
  const float* er = enc + (size_t)bs * 512;
  float a0 = 0.f, a1 = 0.f, a2 = 0.f, a3 = 0.f;
  for (int d = 0; d < 512; d += 4) {
    f32x4 e4 = *(const f32x4*)(er + d);
    f32x4 w0 = *(const f32x4*)(wT + (size_t)(d + 0) * 256 + h4 * 4);
    f32x4 w1 = *(const f32x4*)(wT + (size_t)(d + 1) * 256 + h4 * 4);
    f32x4 w2 = *(const f32x4*)(wT + (size_t)(d + 2) * 256 + h4 * 4);
    f32x4 w3 = *(const f32x4*)(wT + (size_t)(d + 3) * 256 + h4 * 4);
    a0 = fmaf(e4.x, w0.x, a0); a1 = fmaf(e4.x, w0.y, a1); a2 = fmaf(e4.x, w0.z, a2); a3 = fmaf(e4.x, w0.w, a3);
    a0 = fmaf(e4.y, w1.x, a0); a1 = fmaf(e4.y, w1.y, a1); a2 = fmaf(e4.y, w1.z, a2); a3 = fmaf(e4.y, w1.w, a3);
    a0 = fmaf(e4.z, w2.x, a0); a1 = fmaf(e4.z, w2.y, a1); a2 = fmaf(e4.z, w2.z, a2); a3 = fmaf(e4.z, w2.w, a3);
    a0 = fmaf(e4.w, w3.x, a0); a1 = fmaf(e4.w, w3.y, a1); a2 = fmaf(e4.w, w3.z, a2); a3 = fmaf(e4.w, w3.w, a3);
  }
  int h = h4 * 4;
  a0 += pb[h + 0]; a1 += pb[h + 1]; a2 += pb[h + 2]; a3 += pb[h + 3];
  size_t base = ((size_t)b * NH) * NL2 + s;
  kvT[base + (size_t)(h + 0) * NL2] = (_Float16)a0;
  kvT[base + (size_t)(h + 1) * NL2] = (_Float16)a1;
  kvT[base + (size_t)(h + 2) * NL2] = (_Float16)a2;
  kvT[base + (size_t)(h + 3) * NL2] = (_Float16)a3;
}

// kprojL[b][l][g] = sum_h kvT[b][h][l] * wk[g][h], for l < 257 (f16 out)
__global__ __launch_bounds__(256) void kproj0_kernel(const _Float16* __restrict__ kvT,
                                                     const float* __restrict__ wk,
                                                     _Float16* __restrict__ kprojL) {
  int b = blockIdx.x >> 3, gq = blockIdx.x & 7;
  __shared__ float wks[32][256];
  __shared__ float pk[32][8];
  int tid = threadIdx.x;
  for (int i = tid; i < 32 * 256; i += 256) {
    int g = i >> 8, h = i & 255;
    wks[g][h] = wk[(size_t)(gq * 32 + g) * 256 + h];
  }
  __syncthreads();
  {
    int l = tid;   // l in [0,256)
    float acc[32];
#pragma unroll
    for (int g = 0; g < 32; ++g) acc[g] = 0.f;
    for (int h = 0; h < 256; ++h) {
      float kvv = (float)kvT[((size_t)(b * NH + h)) * NL2 + l];
#pragma unroll
      for (int g = 0; g < 32; ++g) acc[g] = fmaf(kvv, wks[g][h], acc[g]);
    }
    for (int g = 0; g < 32; ++g)
      kprojL[((size_t)b * NL2 + l) * NH + gq * 32 + g] = (_Float16)acc[g];
  }
  // l == 256 handled cooperatively
  {
    int g = tid >> 3, hc = tid & 7;
    float acc = 0.f;
    for (int h = hc * 32; h < hc * 32 + 32; ++h)
      acc += (float)kvT[((size_t)(b * NH + h)) * NL2 + 256] * wks[g][h];
    pk[g][hc] = acc;
    __syncthreads();
    if (tid < 32) {
      float sv = 0.f;
      for (int c = 0; c < 8; ++c) sv += pk[tid][c];
      kprojL[((size_t)b * NL2 + 256) * NH + gq * 32 + tid] = (_Float16)sv;
    }
  }
}

// ---------------- sequential scan: one WG per batch; f16 weights+kv+kproj, fp32 state ----------------

__global__ __launch_bounds__(1024) void scan_kernel(
    const int* __restrict__ x, const float* __restrict__ efs, const float* __restrict__ emb,
    const float* __restrict__ wv,
    const float* __restrict__ bih0, const float* __restrict__ bhh0,
    const float* __restrict__ bih1, const float* __restrict__ bhh1,
    const _Float16* __restrict__ wq16, const _Float16* __restrict__ wk16,
    const _Float16* __restrict__ wih0_16, const _Float16* __restrict__ whh0_16,
    const _Float16* __restrict__ wih1_16, const _Float16* __restrict__ whh1_16,
    _Float16* __restrict__ kvT, _Float16* __restrict__ kprojL,
    unsigned short* __restrict__ outs_bf, float* __restrict__ attn_out) {
  __shared__ __align__(16) float h0s[256], h1s[256], qf[256];
  __shared__ __align__(16) float sc[512], sp[2][512];
  __shared__ __align__(16) float ctxp[4][256];
  __shared__ __align__(16) float gi[768], gh[768], wvs[256], red[32];
  __shared__ __align__(16) _Float16 h0h[256], h1h[256], xin16[512], attnh[512];

  int tid = threadIdx.x;
  int b = blockIdx.x;

  if (tid < 256) {
    float h0v = efs[(size_t)(0 * NB + b) * NH + tid] + efs[(size_t)(1 * NB + b) * NH + tid];
    float h1v = efs[(size_t)(2 * NB + b) * NH + tid] + efs[(size_t)(3 * NB + b) * NH + tid];
    h0s[tid] = h0v; h0h[tid] = (_Float16)h0v;
    h1s[tid] = h1v; h1h[tid] = (_Float16)h1v;
    wvs[tid] = wv[tid];
  }
  __syncthreads();

  for (int t = 0; t < NT; ++t) {
    int Lt = NTP1 + t;
    // -- phase 1: emb gather + q = h1 @ wq^T (f16 weights, fp32 acc)
    if (tid < 256) {
      int tok = x[b * NT + t];
      xin16[256 + tid] = (_Float16)emb[(size_t)tok * 256 + tid];
      qf[tid] = dotf16(wq16 + (size_t)tid * 256, h1h, 256, 0.f);
    }
    __syncthreads();
    // -- phase 2: scores; f16 kproj rows g-contiguous, fp32 q/wv/tanh
    {
      int half = tid >> 9, l = tid & 511;
      float acc = 0.f;
      if (l < Lt) {
        const _Float16* kp = kprojL + ((size_t)b * NL2 + l) * NH + half * 128;
        const float* qh = qf + half * 128;
        const float* wh = wvs + half * 128;
#pragma unroll 4
        for (int g = 0; g < 128; g += 8) {
          u32x4 k8 = *(const u32x4*)(kp + g);
          half2v p0 = h2(k8.x), p1 = h2(k8.y), p2 = h2(k8.z), p3 = h2(k8.w);
          f32x4 qa = *(const f32x4*)(qh + g);
          f32x4 qb = *(const f32x4*)(qh + g + 4);
          f32x4 wa = *(const f32x4*)(wh + g);
          f32x4 wb = *(const f32x4*)(wh + g + 4);
          acc = fmaf(wa.x, fast_tanh((float)p0[0] + qa.x), acc);
          acc = fmaf(wa.y, fast_tanh((float)p0[1] + qa.y), acc);
          acc = fmaf(wa.z, fast_tanh((float)p1[0] + qa.z), acc);
          acc = fmaf(wa.w, fast_tanh((float)p1[1] + qa.w), acc);
          acc = fmaf(wb.x, fast_tanh((float)p2[0] + qb.x), acc);
          acc = fmaf(wb.y, fast_tanh((float)p2[1] + qb.y), acc);
          acc = fmaf(wb.z, fast_tanh((float)p3[0] + qb.z), acc);
          acc = fmaf(wb.w, fast_tanh((float)p3[1] + qb.w), acc);
        }
      }
      sp[half][l] = acc;
    }
    __syncthreads();
    // -- phase 3: combine + softmax (xor butterfly reductions)
    {
      float v = (tid < 512 && tid < Lt) ? (sp[0][tid] + sp[1][tid]) : -3.0e38f;
      if (tid < 512) sc[tid] = v;
      for (int off = 32; off; off >>= 1) v = fmaxf(v, __shfl_xor(v, off, 64));
      if ((tid & 63) == 0) red[tid >> 6] = v;
    }
    __syncthreads();
    if (tid == 0) {
      float m = red[0];
      for (int i = 1; i < 16; ++i) m = fmaxf(m, red[i]);
      red[16] = m;
    }
    __syncthreads();
    {
      float M = red[16];
      float e = 0.f;
      if (tid < 512) {
        e = (tid < Lt) ? __expf(sc[tid] - M) : 0.f;
        sc[tid] = e;
      }
      float v = e;
      for (int off = 32; off; off >>= 1) v += __shfl_xor(v, off, 64);
      if ((tid & 63) == 0) red[tid >> 6] = v;
    }
    __syncthreads();
    if (tid == 0) {
      float z = 0.f;
      for (int i = 0; i < 16; ++i) z += red[i];
      red[17] = z;
    }
    __syncthreads();
    {
      float Z = red[17];
      if (tid < 512) {
        float a = __fdividef(sc[tid], Z);            // exact 0 for invalid slots
        attn_out[((size_t)(b * NT + t)) * NL2 + tid] = a;
        attnh[tid] = (_Float16)a;
      }
    }
    __syncthreads();
    // -- phase 4: context = attn @ kv (f16 stream, fp32 acc), bounded by Lt
    {
      int h = tid & 255, qq = tid >> 8;
      int base = qq * 128;
      int len = Lt - base; len = len < 0 ? 0 : (len > 128 ? 128 : len);
      len = (len + 15) & ~15;                        // attn==0 / kv==0 padding is safe
      const _Float16* kvr = kvT + ((size_t)(b * NH + h)) * NL2 + base;
      ctxp[qq][h] = dotf16(kvr, attnh + base, len, 0.f);
    }
    __syncthreads();
    if (tid < 256)
      xin16[tid] = (_Float16)(ctxp[0][tid] + ctxp[1][tid] + ctxp[2][tid] + ctxp[3][tid]);
    __syncthreads();
    // -- phase 5: GRU layer 0 (f16 weights/activations, fp32 gates+state)
    if (tid < 768) {
      gi[tid] = dotf16(wih0_16 + (size_t)tid * 512, xin16, 512, bih0[tid]);
      gh[tid] = dotf16(whh0_16 + (size_t)tid * 256, h0h, 256, bhh0[tid]);
    }
    __syncthreads();
    if (tid < 256) {
      float r = fast_sigmoid(gi[tid] + gh[tid]);
      float z = fast_sigmoid(gi[256 + tid] + gh[256 + tid]);
      float n = fast_tanh(gi[512 + tid] + r * gh[512 + tid]);
      float hn = (1.f - z) * n + z * h0s[tid];
      h0s[tid] = hn; h0h[tid] = (_Float16)hn;
    }
    __syncthreads();
    // -- phase 6: GRU layer 1
    if (tid < 768) {
      gi[tid] = dotf16(wih1_16 + (size_t)tid * 256, h0h, 256, bih1[tid]);
      gh[tid] = dotf16(whh1_16 + (size_t)tid * 256, h1h, 256, bhh1[tid]);
    }
    __syncthreads();
    if (tid < 256) {
      float r = fast_sigmoid(gi[tid] + gh[tid]);
      float z = fast_sigmoid(gi[256 + tid] + gh[256 + tid]);
      float n = fast_tanh(gi[512 + tid] + r * gh[512 + tid]);
      float hn = (1.f - z) * n + z * h1s[tid];
      h1s[tid] = hn; h1h[tid] = (_Float16)hn;
      outs_bf[((size_t)(b * NT + t)) * NH + tid] = f2bf(hn);
    }
    __syncthreads();
    // -- phase 7: append kv column + kproj row at pos = 257+t
    if (t < NT - 1 && tid < 256) {
      int pos = NTP1 + t;
      kvT[((size_t)(b * NH + tid)) * NL2 + pos] = (_Float16)h1s[tid];
      kprojL[((size_t)b * NL2 + pos) * NH + tid] =
          (_Float16)dotf16(wk16 + (size_t)tid * 256, h1h, 256, 0.f);
    }
    __syncthreads();
  }
}

// ---------------- logits GEMM: C(8192x32000) = A(8192x256) * B^T + bias, bf16 MFMA ----------------

__global__ __launch_bounds__(256) void logits_gemm(const unsigned short* __restrict__ A,
                                                   const unsigned short* __restrict__ Bw,
                                                   const float* __restrict__ bias,
                                                   float* __restrict__ C) {
  __shared__ unsigned short As[128][88];
  __shared__ unsigned short Bs[128][88];
  int tid = threadIdx.x;
  int nt = blockIdx.x % 250, mt = blockIdx.x / 250;
  int m0 = mt * 128, n0 = nt * 128;
  int lane = tid & 63, w = tid >> 6;
  int wm = w & 1, wn = w >> 1;
  f32x4 acc[4][4];
#pragma unroll
  for (int m = 0; m < 4; ++m)
#pragma unroll
    for (int n = 0; n < 4; ++n) acc[m][n] = (f32x4)0.0f;

  int r0 = tid >> 3;
  int c0 = (tid & 7) * 8;
  for (int kt = 0; kt < 4; ++kt) {
    __syncthreads();
#pragma unroll
    for (int it = 0; it < 4; ++it) {
      int row = it * 32 + r0;
      u32x4 va = *(const u32x4*)(A + (size_t)(m0 + row) * 256 + kt * 64 + c0);
      u32x4 vb = *(const u32x4*)(Bw + (size_t)(n0 + row) * 256 + kt * 64 + c0);
      *(u32x4*)(&As[row][c0]) = va;
      *(u32x4*)(&Bs[row][c0]) = vb;
    }
    __syncthreads();
#pragma unroll
    for (int ks = 0; ks < 2; ++ks) {
      s16x8 af[4], bf[4];
#pragma unroll
      for (int m = 0; m < 4; ++m)
        af[m] = *(const s16x8*)(&As[wm * 64 + m * 16 + (lane & 15)][ks * 32 + (lane >> 4) * 8]);
#pragma unroll
      for (int n = 0; n < 4; ++n)
        bf[n] = *(const s16x8*)(&Bs[wn * 64 + n * 16 + (lane & 15)][ks * 32 + (lane >> 4) * 8]);
#pragma unroll
      for (int m = 0; m < 4; ++m)
#pragma unroll
        for (int n = 0; n < 4; ++n)
          acc[m][n] = __builtin_amdgcn_mfma_f32_16x16x32_bf16(af[m], bf[n], acc[m][n], 0, 0, 0);
    }
  }
#pragma unroll
  for (int n = 0; n < 4; ++n) {
    int col = n0 + wn * 64 + n * 16 + (lane & 15);
    float bv = bias[col];
#pragma unroll
    for (int m = 0; m < 4; ++m) {
      int rowb = m0 + wm * 64 + m * 16 + (lane >> 4) * 4;
#pragma unroll
      for (int r = 0; r < 4; ++r)
        C[(size_t)(rowb + r) * NV + col] = acc[m][n][r] + bv;
    }
  }
}

// ---------------- host launch ----------------

extern "C" void kernel_launch(void* const* d_in, const int* in_sizes, int n_in,
                              void* d_out, int out_size, void* d_ws, size_t ws_size,
                              hipStream_t stream) {
  const int*   x    = (const int*)d_in[0];
  const float* enc  = (const float*)d_in[1];
  const float* efs  = (const float*)d_in[2];
  const float* emb  = (const float*)d_in[3];
  const float* epw  = (const float*)d_in[4];
  const float* epb  = (const float*)d_in[5];
  const float* wq   = (const float*)d_in[6];
  const float* wk   = (const float*)d_in[7];
  const float* wv   = (const float*)d_in[8];
  const float* wih0 = (const float*)d_in[9];
  const float* whh0 = (const float*)d_in[10];
  const float* bih0 = (const float*)d_in[11];
  const float* bhh0 = (const float*)d_in[12];
  const float* wih1 = (const float*)d_in[13];
  const float* whh1 = (const float*)d_in[14];
  const float* bih1 = (const float*)d_in[15];
  const float* bhh1 = (const float*)d_in[16];
  const float* dw   = (const float*)d_in[17];
  const float* db   = (const float*)d_in[18];

  // workspace layout (bytes); f16 weights alias dwbf16 region (conv_bf16 runs AFTER scan)
  const size_t o_dwbf   = 0;                        // 16,384,000
  const size_t o_wT     = o_dwbf + 16384000;        // 524,288
  const size_t o_kvT    = o_wT + 524288;            // 8,388,608 (f16)
  const size_t o_kproj  = o_kvT + 8388608;          // 8,388,608 (f16)
  const size_t o_outs   = o_kproj + 8388608;        // 4,194,304 (bf16)
  const size_t need     = o_outs + 4194304;         // ~37.9 MB
  if (ws_size < need) return;  // fail visibly rather than corrupt

  char* ws = (char*)d_ws;
  unsigned short* dwbf16 = (unsigned short*)(ws + o_dwbf);
  _Float16* wq16    = (_Float16*)(ws + o_dwbf);            // 131,072 B
  _Float16* wk16    = (_Float16*)(ws + o_dwbf + 131072);   // 131,072 B
  _Float16* wih0_16 = (_Float16*)(ws + o_dwbf + 262144);   // 786,432 B
  _Float16* whh0_16 = (_Float16*)(ws + o_dwbf + 1048576);  // 393,216 B
  _Float16* wih1_16 = (_Float16*)(ws + o_dwbf + 1441792);  // 393,216 B
  _Float16* whh1_16 = (_Float16*)(ws + o_dwbf + 1835008);  // 393,216 B
  float* wT          = (float*)(ws + o_wT);
  _Float16* kvT      = (_Float16*)(ws + o_kvT);
  _Float16* kprojL   = (_Float16*)(ws + o_kproj);
  unsigned short* outs_bf = (unsigned short*)(ws + o_outs);

  float* logits = (float*)d_out;
  float* attn_out = logits + (size_t)NB * NT * NV;

  // zero-init KV buffers (invalid slots must be finite zeros)
  hipMemsetAsync(ws + o_kvT, 0, 2 * 8388608, stream);

  // f16 weight conversions (into the region later overwritten by dwbf16)
  conv_f16_kernel<<<(65536 + 255) / 256, 256, 0, stream>>>(wq, wq16, 65536);
  conv_f16_kernel<<<(65536 + 255) / 256, 256, 0, stream>>>(wk, wk16, 65536);
  conv_f16_kernel<<<(393216 + 255) / 256, 256, 0, stream>>>(wih0, wih0_16, 393216);
  conv_f16_kernel<<<(196608 + 255) / 256, 256, 0, stream>>>(whh0, whh0_16, 196608);
  conv_f16_kernel<<<(196608 + 255) / 256, 256, 0, stream>>>(wih1, wih1_16, 196608);
  conv_f16_kernel<<<(196608 + 255) / 256, 256, 0, stream>>>(whh1, whh1_16, 196608);
  transpose_kernel<<<(131072 + 255) / 256, 256, 0, stream>>>(epw, wT);

  // encoder projection -> kvT (f16), then key projections -> kprojL [b][l][g] (f16)
  proj_kernel<<<(NTP1 * NB * 64) / 256, 256, 0, stream>>>(enc, wT, epb, kvT);
  kproj0_kernel<<<NB * 8, 256, 0, stream>>>(kvT, wk, kprojL);

  // sequential scan: one workgroup per batch
  scan_kernel<<<NB, 1024, 0, stream>>>(x, efs, emb, wv, bih0, bhh0, bih1, bhh1,
                                       wq16, wk16, wih0_16, whh0_16, wih1_16, whh1_16,
                                       kvT, kprojL, outs_bf, attn_out);

  // now safe to overwrite the f16-weight region with bf16 dense_w
  conv_bf16_kernel<<<(8192000 + 255) / 256, 256, 0, stream>>>(dw, dwbf16, 8192000);

  // final big GEMM: logits
  logits_gemm<<<(NB * NT / 128) * (NV / 128), 256, 0, stream>>>(outs_bf, dwbf16, db, logits);
}

// Round 5
// 15886.540 us; speedup vs baseline: 2.6360x; 1.4663x over previous
//
#include <hip/hip_runtime.h>
#include <hip/hip_bf16.h>
#include <hip/hip_fp16.h>

// Problem sizes
#define NB 32
#define NT 256
#define NH 256
#define NV 32000
#define NL2 512     // fixed KV length = 2T
#define NTP1 257    // T+1

typedef unsigned int u32x4 __attribute__((ext_vector_type(4)));
typedef short s16x8 __attribute__((ext_vector_type(8)));
typedef float f32x4 __attribute__((ext_vector_type(4)));
typedef _Float16 half2v __attribute__((ext_vector_type(2)));

__device__ __forceinline__ float dot2f(half2v a, half2v b, float c) {
#if __has_builtin(__builtin_amdgcn_fdot2)
  return __builtin_amdgcn_fdot2(a, b, c, false);
#else
  return c + (float)a[0] * (float)b[0] + (float)a[1] * (float)b[1];
#endif
}
__device__ __forceinline__ half2v h2(unsigned int u) { return __builtin_bit_cast(half2v, u); }

// f16 dot: w global (b128 loads), x LDS. n multiple of 16. fp32 accumulate.
__device__ __forceinline__ float dotf16(const _Float16* __restrict__ w,
                                        const _Float16* __restrict__ x, int n, float acc) {
#pragma unroll 8
  for (int k = 0; k < n; k += 16) {
    u32x4 a0 = *(const u32x4*)(w + k);
    u32x4 a1 = *(const u32x4*)(w + k + 8);
    u32x4 b0 = *(const u32x4*)(x + k);
    u32x4 b1 = *(const u32x4*)(x + k + 8);
    acc = dot2f(h2(a0.x), h2(b0.x), acc);
    acc = dot2f(h2(a0.y), h2(b0.y), acc);
    acc = dot2f(h2(a0.z), h2(b0.z), acc);
    acc = dot2f(h2(a0.w), h2(b0.w), acc);
    acc = dot2f(h2(a1.x), h2(b1.x), acc);
    acc = dot2f(h2(a1.y), h2(b1.y), acc);
    acc = dot2f(h2(a1.z), h2(b1.z), acc);
    acc = dot2f(h2(a1.w), h2(b1.w), acc);
  }
  return acc;
}

// 16-element f16 dot (one 32B chunk), fp32 acc
__device__ __forceinline__ float dot16h(const _Float16* __restrict__ w,
                                        const _Float16* __restrict__ x) {
  u32x4 a0 = *(const u32x4*)w;
  u32x4 a1 = *(const u32x4*)(w + 8);
  u32x4 b0 = *(const u32x4*)x;
  u32x4 b1 = *(const u32x4*)(x + 8);
  float acc = 0.f;
  acc = dot2f(h2(a0.x), h2(b0.x), acc);
  acc = dot2f(h2(a0.y), h2(b0.y), acc);
  acc = dot2f(h2(a0.z), h2(b0.z), acc);
  acc = dot2f(h2(a0.w), h2(b0.w), acc);
  acc = dot2f(h2(a1.x), h2(b1.x), acc);
  acc = dot2f(h2(a1.y), h2(b1.y), acc);
  acc = dot2f(h2(a1.z), h2(b1.z), acc);
  acc = dot2f(h2(a1.w), h2(b1.w), acc);
  return acc;
}

__device__ __forceinline__ float fast_tanh(float x) {
  x = fminf(15.f, fmaxf(-15.f, x));
  float e = __expf(2.f * x);
  return 1.f - __fdividef(2.f, e + 1.f);
}
__device__ __forceinline__ float fast_sigmoid(float x) {
  x = fminf(30.f, fmaxf(-30.f, x));
  float e = __expf(-x);
  return __fdividef(1.f, 1.f + e);
}
__device__ __forceinline__ unsigned short f2bf(float f) {  // RNE fp32->bf16
  unsigned int u = __builtin_bit_cast(unsigned int, f);
  return (unsigned short)((u + 0x7FFFu + ((u >> 16) & 1u)) >> 16);
}

// device-scope per-batch barrier: monotonic counter, target = NPART*(epoch)
__device__ __forceinline__ void batch_barrier(int* __restrict__ ctr, int target) {
  __syncthreads();
  if (threadIdx.x == 0) {
    __threadfence();                       // release: make our global writes visible
    atomicAdd(ctr, 1);
    while (__hip_atomic_load(ctr, __ATOMIC_RELAXED, __HIP_MEMORY_SCOPE_AGENT) < target) {
      __builtin_amdgcn_s_sleep(2);
    }
    __threadfence();                       // acquire: invalidate stale cached lines
  }
  __syncthreads();
}

// ---------------- setup kernels ----------------

__global__ void conv_f16_kernel(const float* __restrict__ s, _Float16* __restrict__ d, int n) {
  int i = blockIdx.x * 256 + threadIdx.x;
  if (i < n) d[i] = (_Float16)s[i];
}

__global__ void conv_bf16_kernel(const float* __restrict__ s, unsigned short* __restrict__ d, int n) {
  int i = blockIdx.x * 256 + threadIdx.x;
  if (i < n) d[i] = f2bf(s[i]);
}

// enc_proj_w (256,512) -> wT (512,256)
__global__ void transpose_kernel(const float* __restrict__ w, float* __restrict__ wT) {
  int i = blockIdx.x * 256 + threadIdx.x;
  if (i < 256 * 512) { int h = i >> 9, dd = i & 511; wT[dd * 256 + h] = w[i]; }
}

// proj[b,s,h] = enc_proj_b[h] + sum_d enc[s,b,d]*W[h,d]; write kvT[b][h][s] (f16)
__global__ __launch_bounds__(256) void proj_kernel(const float* __restrict__ enc,
                                                   const float* __restrict__ wT,
                                                   const float* __restrict__ pb,
                                                   _Float16* __restrict__ kvT) {
  int gid = blockIdx.x * 256 + threadIdx.x;
  int h4 = gid & 63;
  int bs = gid >> 6;                 // = s*32 + b (matches enc layout)
  if (bs >= NTP1 * NB) return;
  int s = bs >> 5, b = bs & 31;
  const float* er = enc + (size_t)bs * 512;
  float a0 = 0.f, a1 = 0.f, a2 = 0.f, a3 = 0.f;
  for (int d = 0; d < 512; d += 4) {
    f32x4 e4 = *(const f32x4*)(er + d);
    f32x4 w0 = *(const f32x4*)(wT + (size_t)(d + 0) * 256 + h4 * 4);
    f32x4 w1 = *(const f32x4*)(wT + (size_t)(d + 1) * 256 + h4 * 4);
    f32x4 w2 = *(const f32x4*)(wT + (size_t)(d + 2) * 256 + h4 * 4);
    f32x4 w3 = *(const f32x4*)(wT + (size_t)(d + 3) * 256 + h4 * 4);
    a0 = fmaf(e4.x, w0.x, a0); a1 = fmaf(e4.x, w0.y, a1); a2 = fmaf(e4.x, w0.z, a2); a3 = fmaf(e4.x, w0.w, a3);
    a0 = fmaf(e4.y, w1.x, a0); a1 = fmaf(e4.y, w1.y, a1); a2 = fmaf(e4.y, w1.z, a2); a3 = fmaf(e4.y, w1.w, a3);
    a0 = fmaf(e4.z, w2.x, a0); a1 = fmaf(e4.z, w2.y, a1); a2 = fmaf(e4.z, w2.z, a2); a3 = fmaf(e4.z, w2.w, a3);
    a0 = fmaf(e4.w, w3.x, a0); a1 = fmaf(e4.w, w3.y, a1); a2 = fmaf(e4.w, w3.z, a2); a3 = fmaf(e4.w, w3.w, a3);
  }
  int h = h4 * 4;
  a0 += pb[h + 0]; a1 += pb[h + 1]; a2 += pb[h + 2]; a3 += pb[h + 3];
  size_t base = ((size_t)b * NH) * NL2 + s;
  kvT[base + (size_t)(h + 0) * NL2] = (_Float16)a0;
  kvT[base + (size_t)(h + 1) * NL2] = (_Float16)a1;
  kvT[base + (size_t)(h + 2) * NL2] = (_Float16)a2;
  kvT[base + (size_t)(h + 3) * NL2] = (_Float16)a3;
}

// kprojL[b][l][g] = sum_h kvT[b][h][l] * wk[g][h], for l < 257 (f16 out)
__global__ __launch_bounds__(256) void kproj0_kernel(const _Float16* __restrict__ kvT,
                                                     const float* __restrict__ wk,
                                                     _Float16* __restrict__ kprojL) {
  int b = blockIdx.x >> 3, gq = blockIdx.x & 7;
  __shared__ float wks[32][256];
  __shared__ float pk[32][8];
  int tid = threadIdx.x;
  for (int i = tid; i < 32 * 256; i += 256) {
    int g = i >> 8, h = i & 255;
    wks[g][h] = wk[(size_t)(gq * 32 + g) * 256 + h];
  }
  __syncthreads();
  {
    int l = tid;   // l in [0,256)
    float acc[32];
#pragma unroll
    for (int g = 0; g < 32; ++g) acc[g] = 0.f;
    for (int h = 0; h < 256; ++h) {
      float kvv = (float)kvT[((size_t)(b * NH + h)) * NL2 + l];
#pragma unroll
      for (int g = 0; g < 32; ++g) acc[g] = fmaf(kvv, wks[g][h], acc[g]);
    }
    for (int g = 0; g < 32; ++g)
      kprojL[((size_t)b * NL2 + l) * NH + gq * 32 + g] = (_Float16)acc[g];
  }
  // l == 256 handled cooperatively
  {
    int g = tid >> 3, hc = tid & 7;
    float acc = 0.f;
    for (int h = hc * 32; h < hc * 32 + 32; ++h)
      acc += (float)kvT[((size_t)(b * NH + h)) * NL2 + 256] * wks[g][h];
    pk[g][hc] = acc;
    __syncthreads();
    if (tid < 32) {
      float sv = 0.f;
      for (int c = 0; c < 8; ++c) sv += pk[tid][c];
      kprojL[((size_t)b * NL2 + 256) * NH + gq * 32 + tid] = (_Float16)sv;
    }
  }
}

// ---------------- cooperative scan: 8 WGs per batch, 5 device barriers/step ----------------
// blockIdx: b = blk & 31, s = blk >> 5  (stride-32 so a batch's 8 WGs share an XCD if idx%8 maps)

__global__ __launch_bounds__(512) void scan_kernel(
    const int* __restrict__ x, const float* __restrict__ efs, const float* __restrict__ emb,
    const float* __restrict__ wv,
    const float* __restrict__ bih0, const float* __restrict__ bhh0,
    const float* __restrict__ bih1, const float* __restrict__ bhh1,
    const _Float16* __restrict__ wq16, const _Float16* __restrict__ wk16,
    const _Float16* __restrict__ wih0_16, const _Float16* __restrict__ whh0_16,
    const _Float16* __restrict__ wih1_16, const _Float16* __restrict__ whh1_16,
    _Float16* __restrict__ kvT, _Float16* __restrict__ kprojL,
    float* __restrict__ q_g, float* __restrict__ scores_g, _Float16* __restrict__ xin_g,
    float* __restrict__ g0i_g, float* __restrict__ g0h_g,
    float* __restrict__ g1i_g, float* __restrict__ g1h_g,
    int* __restrict__ bars,
    unsigned short* __restrict__ outs_bf, float* __restrict__ attn_out) {
  __shared__ __align__(16) float h0s[256], h1s[256], qf[256], attns[512], wvs[256], red[16];
  __shared__ __align__(16) _Float16 h0h[256], h1h[256], xinh[512];

  int tid = threadIdx.x;
  int b = blockIdx.x & 31;
  int s = blockIdx.x >> 5;
  int* bar = bars + b * 32;

  // redundant per-WG state init
  if (tid < 256) {
    float h0v = efs[(size_t)(0 * NB + b) * NH + tid] + efs[(size_t)(1 * NB + b) * NH + tid];
    float h1v = efs[(size_t)(2 * NB + b) * NH + tid] + efs[(size_t)(3 * NB + b) * NH + tid];
    h0s[tid] = h0v; h0h[tid] = (_Float16)h0v;
    h1s[tid] = h1v; h1h[tid] = (_Float16)h1v;
    wvs[tid] = wv[tid];
  }
  __syncthreads();

  for (int t = 0; t < NT; ++t) {
    int Lt = NTP1 + t;
    int tgt = 8 * (t + 1);
    // -- A: q slice (rows 32s..32s+31), emb slice -> xin_g[256+32s..]
    {
      int row = tid >> 4, sub = tid & 15;
      int R = 32 * s + row;
      float a = dot16h(wq16 + (size_t)R * 256 + sub * 16, h1h + sub * 16);
      a += __shfl_xor(a, 1); a += __shfl_xor(a, 2);
      a += __shfl_xor(a, 4); a += __shfl_xor(a, 8);
      if (sub == 0) q_g[b * 256 + R] = a;
      if (tid < 32) {
        int tok = x[b * NT + t];
        xin_g[b * 512 + 256 + 32 * s + tid] = (_Float16)emb[(size_t)tok * 256 + 32 * s + tid];
      }
    }
    batch_barrier(bar + 0, tgt);   // q, emb, and prev-step kproj append visible
    // -- B: scores slice (l in [64s, 64s+64))
    if (tid < 256) qf[tid] = q_g[b * 256 + tid];
    __syncthreads();
    {
      int l = 64 * s + (tid >> 3), sub = tid & 7;
      if (l < Lt) {
        const _Float16* kp = kprojL + ((size_t)b * NL2 + l) * NH + sub * 32;
        const float* qh = qf + sub * 32;
        const float* wh = wvs + sub * 32;
        float a = 0.f;
#pragma unroll
        for (int g = 0; g < 32; g += 8) {
          u32x4 k8 = *(const u32x4*)(kp + g);
          half2v p0 = h2(k8.x), p1 = h2(k8.y), p2 = h2(k8.z), p3 = h2(k8.w);
          f32x4 qa = *(const f32x4*)(qh + g);
          f32x4 qb = *(const f32x4*)(qh + g + 4);
          f32x4 wa = *(const f32x4*)(wh + g);
          f32x4 wb = *(const f32x4*)(wh + g + 4);
          a = fmaf(wa.x, fast_tanh((float)p0[0] + qa.x), a);
          a = fmaf(wa.y, fast_tanh((float)p0[1] + qa.y), a);
          a = fmaf(wa.z, fast_tanh((float)p1[0] + qa.z), a);
          a = fmaf(wa.w, fast_tanh((float)p1[1] + qa.w), a);
          a = fmaf(wb.x, fast_tanh((float)p2[0] + qb.x), a);
          a = fmaf(wb.y, fast_tanh((float)p2[1] + qb.y), a);
          a = fmaf(wb.z, fast_tanh((float)p3[0] + qb.z), a);
          a = fmaf(wb.w, fast_tanh((float)p3[1] + qb.w), a);
        }
        a += __shfl_xor(a, 1); a += __shfl_xor(a, 2); a += __shfl_xor(a, 4);
        if (sub == 0) scores_g[b * 512 + l] = a;
      }
    }
    batch_barrier(bar + 1, tgt);   // all scores visible
    // -- C: softmax (redundant in every WG), attn_out slice write
    {
      float v = (tid < Lt) ? scores_g[b * 512 + tid] : -3.0e38f;
      float m = v;
#pragma unroll
      for (int off = 32; off; off >>= 1) m = fmaxf(m, __shfl_xor(m, off, 64));
      if ((tid & 63) == 0) red[tid >> 6] = m;
      __syncthreads();
      float M = red[0];
#pragma unroll
      for (int i = 1; i < 8; ++i) M = fmaxf(M, red[i]);
      float e = (tid < Lt) ? __expf(v - M) : 0.f;
      float zz = e;
#pragma unroll
      for (int off = 32; off; off >>= 1) zz += __shfl_xor(zz, off, 64);
      if ((tid & 63) == 0) red[8 + (tid >> 6)] = zz;
      __syncthreads();
      float Z = red[8];
#pragma unroll
      for (int i = 1; i < 8; ++i) Z += red[8 + i];
      float a = __fdividef(e, Z);          // exact 0 for invalid slots
      attns[tid] = a;
      if ((tid >> 6) == s) attn_out[((size_t)(b * NT + t)) * NL2 + tid] = a;
    }
    __syncthreads();
    // -- D: context slice (h rows 32s..32s+31)
    {
      int h = 32 * s + (tid >> 4), sub = tid & 15;
      const _Float16* kvr = kvT + ((size_t)(b * NH + h)) * NL2 + sub * 32;
      const float* ar = attns + sub * 32;
      float a = 0.f;
#pragma unroll
      for (int k = 0; k < 32; k += 8) {
        u32x4 v8 = *(const u32x4*)(kvr + k);
        half2v c0 = h2(v8.x), c1 = h2(v8.y), c2 = h2(v8.z), c3 = h2(v8.w);
        a = fmaf((float)c0[0], ar[k + 0], a);
        a = fmaf((float)c0[1], ar[k + 1], a);
        a = fmaf((float)c1[0], ar[k + 2], a);
        a = fmaf((float)c1[1], ar[k + 3], a);
        a = fmaf((float)c2[0], ar[k + 4], a);
        a = fmaf((float)c2[1], ar[k + 5], a);
        a = fmaf((float)c3[0], ar[k + 6], a);
        a = fmaf((float)c3[1], ar[k + 7], a);
      }
      a += __shfl_xor(a, 1); a += __shfl_xor(a, 2);
      a += __shfl_xor(a, 4); a += __shfl_xor(a, 8);
      if (sub == 0) xin_g[b * 512 + h] = (_Float16)a;
    }
    batch_barrier(bar + 2, tgt);   // xin (ctx+emb) visible
    // -- E: GRU0 matvec slice (gate rows 96s..96s+95)
    if (tid < 64) ((u32x4*)xinh)[tid] = *(const u32x4*)(xin_g + (size_t)b * 512 + tid * 8);
    __syncthreads();
    if (tid < 384) {
      int rr = tid >> 2, sub = tid & 3;
      int r = 96 * s + rr;
      float a = dotf16(wih0_16 + (size_t)r * 512 + sub * 128, xinh + sub * 128, 128, 0.f);
      a += __shfl_xor(a, 1); a += __shfl_xor(a, 2);
      if (sub == 0) g0i_g[b * 768 + r] = a + bih0[r];
    } else if (tid < 480) {
      int r = 96 * s + (tid - 384);
      g0h_g[b * 768 + r] = dotf16(whh0_16 + (size_t)r * 256, h0h, 256, bhh0[r]);
    }
    batch_barrier(bar + 3, tgt);   // gates0 visible
    // -- F: h0 combine (redundant)
    if (tid < 256) {
      int j = tid;
      float ir = g0i_g[b * 768 + j],       hr = g0h_g[b * 768 + j];
      float iz = g0i_g[b * 768 + 256 + j], hz = g0h_g[b * 768 + 256 + j];
      float in_ = g0i_g[b * 768 + 512 + j], hn_ = g0h_g[b * 768 + 512 + j];
      float r_ = fast_sigmoid(ir + hr);
      float z_ = fast_sigmoid(iz + hz);
      float n_ = fast_tanh(in_ + r_ * hn_);
      float hv = (1.f - z_) * n_ + z_ * h0s[j];
      h0s[j] = hv; h0h[j] = (_Float16)hv;
    }
    __syncthreads();
    // -- G: GRU1 matvec slice
    if (tid < 384) {
      int rr = tid >> 2, sub = tid & 3;
      int r = 96 * s + rr;
      float a = dotf16(wih1_16 + (size_t)r * 256 + sub * 64, h0h + sub * 64, 64, 0.f);
      a += __shfl_xor(a, 1); a += __shfl_xor(a, 2);
      if (sub == 0) g1i_g[b * 768 + r] = a + bih1[r];
    } else if (tid < 480) {
      int r = 96 * s + (tid - 384);
      g1h_g[b * 768 + r] = dotf16(whh1_16 + (size_t)r * 256, h1h, 256, bhh1[r]);
    }
    batch_barrier(bar + 4, tgt);   // gates1 visible
    // -- H: h1 combine (redundant) + slice writes (outs, kv append)
    if (tid < 256) {
      int j = tid;
      float ir = g1i_g[b * 768 + j],       hr = g1h_g[b * 768 + j];
      float iz = g1i_g[b * 768 + 256 + j], hz = g1h_g[b * 768 + 256 + j];
      float in_ = g1i_g[b * 768 + 512 + j], hn_ = g1h_g[b * 768 + 512 + j];
      float r_ = fast_sigmoid(ir + hr);
      float z_ = fast_sigmoid(iz + hz);
      float n_ = fast_tanh(in_ + r_ * hn_);
      float hv = (1.f - z_) * n_ + z_ * h1s[j];
      h1s[j] = hv; h1h[j] = (_Float16)hv;
      if ((j >> 5) == s) {
        outs_bf[((size_t)(b * NT + t)) * NH + j] = f2bf(hv);
        if (t < NT - 1) kvT[((size_t)(b * NH + j)) * NL2 + NTP1 + t] = (_Float16)hv;
      }
    }
    __syncthreads();
    // -- I: kproj append slice (g rows 32s..32s+31); visible via next step's bar0
    if (t < NT - 1) {
      int row = tid >> 4, sub = tid & 15;
      int g = 32 * s + row;
      float a = dot16h(wk16 + (size_t)g * 256 + sub * 16, h1h + sub * 16);
      a += __shfl_xor(a, 1); a += __shfl_xor(a, 2);
      a += __shfl_xor(a, 4); a += __shfl_xor(a, 8);
      if (sub == 0) kprojL[((size_t)b * NL2 + NTP1 + t) * NH + g] = (_Float16)a;
    }
  }
}

// ---------------- logits GEMM: C(8192x32000) = A(8192x256) * B^T + bias, bf16 MFMA ----------------

__global__ __launch_bounds__(256) void logits_gemm(const unsigned short* __restrict__ A,
                                                   const unsigned short* __restrict__ Bw,
                                                   const float* __restrict__ bias,
                                                   float* __restrict__ C) {
  __shared__ unsigned short As[128][88];
  __shared__ unsigned short Bs[128][88];
  int tid = threadIdx.x;
  int nt = blockIdx.x % 250, mt = blockIdx.x / 250;
  int m0 = mt * 128, n0 = nt * 128;
  int lane = tid & 63, w = tid >> 6;
  int wm = w & 1, wn = w >> 1;
  f32x4 acc[4][4];
#pragma unroll
  for (int m = 0; m < 4; ++m)
#pragma unroll
    for (int n = 0; n < 4; ++n) acc[m][n] = (f32x4)0.0f;

  int r0 = tid >> 3;
  int c0 = (tid & 7) * 8;
  for (int kt = 0; kt < 4; ++kt) {
    __syncthreads();
#pragma unroll
    for (int it = 0; it < 4; ++it) {
      int row = it * 32 + r0;
      u32x4 va = *(const u32x4*)(A + (size_t)(m0 + row) * 256 + kt * 64 + c0);
      u32x4 vb = *(const u32x4*)(Bw + (size_t)(n0 + row) * 256 + kt * 64 + c0);
      *(u32x4*)(&As[row][c0]) = va;
      *(u32x4*)(&Bs[row][c0]) = vb;
    }
    __syncthreads();
#pragma unroll
    for (int ks = 0; ks < 2; ++ks) {
      s16x8 af[4], bf[4];
#pragma unroll
      for (int m = 0; m < 4; ++m)
        af[m] = *(const s16x8*)(&As[wm * 64 + m * 16 + (lane & 15)][ks * 32 + (lane >> 4) * 8]);
#pragma unroll
      for (int n = 0; n < 4; ++n)
        bf[n] = *(const s16x8*)(&Bs[wn * 64 + n * 16 + (lane & 15)][ks * 32 + (lane >> 4) * 8]);
#pragma unroll
      for (int m = 0; m < 4; ++m)
#pragma unroll
        for (int n = 0; n < 4; ++n)
          acc[m][n] = __builtin_amdgcn_mfma_f32_16x16x32_bf16(af[m], bf[n], acc[m][n], 0, 0, 0);
    }
  }
#pragma unroll
  for (int n = 0; n < 4; ++n) {
    int col = n0 + wn * 64 + n * 16 + (lane & 15);
    float bv = bias[col];
#pragma unroll
    for (int m = 0; m < 4; ++m) {
      int rowb = m0 + wm * 64 + m * 16 + (lane >> 4) * 4;
#pragma unroll
      for (int r = 0; r < 4; ++r)
        C[(size_t)(rowb + r) * NV + col] = acc[m][n][r] + bv;
    }
  }
}

// ---------------- host launch ----------------

extern "C" void kernel_launch(void* const* d_in, const int* in_sizes, int n_in,
                              void* d_out, int out_size, void* d_ws, size_t ws_size,
                              hipStream_t stream) {
  const int*   x    = (const int*)d_in[0];
  const float* enc  = (const float*)d_in[1];
  const float* efs  = (const float*)d_in[2];
  const float* emb  = (const float*)d_in[3];
  const float* epw  = (const float*)d_in[4];
  const float* epb  = (const float*)d_in[5];
  const float* wq   = (const float*)d_in[6];
  const float* wk   = (const float*)d_in[7];
  const float* wv   = (const float*)d_in[8];
  const float* wih0 = (const float*)d_in[9];
  const float* whh0 = (const float*)d_in[10];
  const float* bih0 = (const float*)d_in[11];
  const float* bhh0 = (const float*)d_in[12];
  const float* wih1 = (const float*)d_in[13];
  const float* whh1 = (const float*)d_in[14];
  const float* bih1 = (const float*)d_in[15];
  const float* bhh1 = (const float*)d_in[16];
  const float* dw   = (const float*)d_in[17];
  const float* db   = (const float*)d_in[18];

  // workspace layout (bytes); f16 weights alias dwbf16 region (conv_bf16 runs AFTER scan)
  const size_t o_dwbf   = 0;                        // 16,384,000
  const size_t o_wT     = o_dwbf + 16384000;        // 524,288
  const size_t o_kvT    = o_wT + 524288;            // 8,388,608 (f16)
  const size_t o_kproj  = o_kvT + 8388608;          // 8,388,608 (f16)
  const size_t o_outs   = o_kproj + 8388608;        // 4,194,304 (bf16)
  const size_t o_qg     = o_outs + 4194304;         // 32*256*4   = 32,768
  const size_t o_scores = o_qg + 32768;             // 32*512*4   = 65,536
  const size_t o_xin    = o_scores + 65536;         // 32*512*2   = 32,768
  const size_t o_g0i    = o_xin + 32768;            // 32*768*4   = 98,304
  const size_t o_g0h    = o_g0i + 98304;            // 98,304
  const size_t o_g1i    = o_g0h + 98304;            // 98,304
  const size_t o_g1h    = o_g1i + 98304;            // 98,304
  const size_t o_bar    = o_g1h + 98304;            // 32*32*4    = 4,096
  const size_t need     = o_bar + 4096;             // ~38.4 MB
  if (ws_size < need) return;  // fail visibly rather than corrupt

  char* ws = (char*)d_ws;
  unsigned short* dwbf16 = (unsigned short*)(ws + o_dwbf);
  _Float16* wq16    = (_Float16*)(ws + o_dwbf);            // 131,072 B
  _Float16* wk16    = (_Float16*)(ws + o_dwbf + 131072);   // 131,072 B
  _Float16* wih0_16 = (_Float16*)(ws + o_dwbf + 262144);   // 786,432 B
  _Float16* whh0_16 = (_Float16*)(ws + o_dwbf + 1048576);  // 393,216 B
  _Float16* wih1_16 = (_Float16*)(ws + o_dwbf + 1441792);  // 393,216 B
  _Float16* whh1_16 = (_Float16*)(ws + o_dwbf + 1835008);  // 393,216 B
  float* wT          = (float*)(ws + o_wT);
  _Float16* kvT      = (_Float16*)(ws + o_kvT);
  _Float16* kprojL   = (_Float16*)(ws + o_kproj);
  unsigned short* outs_bf = (unsigned short*)(ws + o_outs);
  float* q_g         = (float*)(ws + o_qg);
  float* scores_g    = (float*)(ws + o_scores);
  _Float16* xin_g    = (_Float16*)(ws + o_xin);
  float* g0i_g       = (float*)(ws + o_g0i);
  float* g0h_g       = (float*)(ws + o_g0h);
  float* g1i_g       = (float*)(ws + o_g1i);
  float* g1h_g       = (float*)(ws + o_g1h);
  int* bars          = (int*)(ws + o_bar);

  float* logits = (float*)d_out;
  float* attn_out = logits + (size_t)NB * NT * NV;

  // zero-init KV buffers (invalid slots must be finite zeros) and barrier counters
  hipMemsetAsync(ws + o_kvT, 0, 2 * 8388608, stream);
  hipMemsetAsync(ws + o_bar, 0, 4096, stream);

  // f16 weight conversions (into the region later overwritten by dwbf16)
  conv_f16_kernel<<<(65536 + 255) / 256, 256, 0, stream>>>(wq, wq16, 65536);
  conv_f16_kernel<<<(65536 + 255) / 256, 256, 0, stream>>>(wk, wk16, 65536);
  conv_f16_kernel<<<(393216 + 255) / 256, 256, 0, stream>>>(wih0, wih0_16, 393216);
  conv_f16_kernel<<<(196608 + 255) / 256, 256, 0, stream>>>(whh0, whh0_16, 196608);
  conv_f16_kernel<<<(196608 + 255) / 256, 256, 0, stream>>>(wih1, wih1_16, 196608);
  conv_f16_kernel<<<(196608 + 255) / 256, 256, 0, stream>>>(whh1, whh1_16, 196608);
  transpose_kernel<<<(131072 + 255) / 256, 256, 0, stream>>>(epw, wT);

  // encoder projection -> kvT (f16), then key projections -> kprojL [b][l][g] (f16)
  proj_kernel<<<(NTP1 * NB * 64) / 256, 256, 0, stream>>>(enc, wT, epb, kvT);
  kproj0_kernel<<<NB * 8, 256, 0, stream>>>(kvT, wk, kprojL);

  // cooperative scan: 256 WGs (8 per batch), 512 threads each — 1 WG/CU co-resident
  scan_kernel<<<256, 512, 0, stream>>>(x, efs, emb, wv, bih0, bhh0, bih1, bhh1,
                                       wq16, wk16, wih0_16, whh0_16, wih1_16, whh1_16,
                                       kvT, kprojL,
                                       q_g, scores_g, xin_g,
                                       g0i_g, g0h_g, g1i_g, g1h_g, bars,
                                       outs_bf, attn_out);

  // now safe to overwrite the f16-weight region with bf16 dense_w
  conv_bf16_kernel<<<(8192000 + 255) / 256, 256, 0, stream>>>(dw, dwbf16, 8192000);

  // final big GEMM: logits
  logits_gemm<<<(NB * NT / 128) * (NV / 128), 256, 0, stream>>>(outs_bf, dwbf16, db, logits);
}

// Round 6
// 8125.389 us; speedup vs baseline: 5.1539x; 1.9552x over previous
//
#include <hip/hip_runtime.h>
#include <hip/hip_bf16.h>
#include <hip/hip_fp16.h>

// Problem sizes
#define NB 32
#define NT 256
#define NH 256
#define NV 32000
#define NL2 512     // fixed KV length = 2T
#define NTP1 257    // T+1
#define KPS 260     // kproj LDS row stride in halves (520B: 8B-aligned, 2-way bank pattern)

typedef unsigned int u32x4 __attribute__((ext_vector_type(4)));
typedef unsigned int u32x2 __attribute__((ext_vector_type(2)));
typedef short s16x8 __attribute__((ext_vector_type(8)));
typedef float f32x4 __attribute__((ext_vector_type(4)));
typedef float f32x2 __attribute__((ext_vector_type(2)));
typedef _Float16 half2v __attribute__((ext_vector_type(2)));

#define AGENT __HIP_MEMORY_SCOPE_AGENT
__device__ __forceinline__ float aload(const float* p) {
  return __hip_atomic_load((float*)p, __ATOMIC_RELAXED, AGENT);
}
__device__ __forceinline__ void astore(float* p, float v) {
  __hip_atomic_store(p, v, __ATOMIC_RELAXED, AGENT);
}
__device__ __forceinline__ unsigned int aloadu(const unsigned int* p) {
  return __hip_atomic_load((unsigned int*)p, __ATOMIC_RELAXED, AGENT);
}
__device__ __forceinline__ void astoreu(unsigned int* p, unsigned int v) {
  __hip_atomic_store(p, v, __ATOMIC_RELAXED, AGENT);
}

__device__ __forceinline__ float dot2f(half2v a, half2v b, float c) {
#if __has_builtin(__builtin_amdgcn_fdot2)
  return __builtin_amdgcn_fdot2(a, b, c, false);
#else
  return c + (float)a[0] * (float)b[0] + (float)a[1] * (float)b[1];
#endif
}
__device__ __forceinline__ half2v h2(unsigned int u) { return __builtin_bit_cast(half2v, u); }

// f16 dot: w global (b128 loads), x LDS. n multiple of 16. fp32 accumulate.
__device__ __forceinline__ float dotf16(const _Float16* __restrict__ w,
                                        const _Float16* __restrict__ x, int n, float acc) {
#pragma unroll 8
  for (int k = 0; k < n; k += 16) {
    u32x4 a0 = *(const u32x4*)(w + k);
    u32x4 a1 = *(const u32x4*)(w + k + 8);
    u32x4 b0 = *(const u32x4*)(x + k);
    u32x4 b1 = *(const u32x4*)(x + k + 8);
    acc = dot2f(h2(a0.x), h2(b0.x), acc);
    acc = dot2f(h2(a0.y), h2(b0.y), acc);
    acc = dot2f(h2(a0.z), h2(b0.z), acc);
    acc = dot2f(h2(a0.w), h2(b0.w), acc);
    acc = dot2f(h2(a1.x), h2(b1.x), acc);
    acc = dot2f(h2(a1.y), h2(b1.y), acc);
    acc = dot2f(h2(a1.z), h2(b1.z), acc);
    acc = dot2f(h2(a1.w), h2(b1.w), acc);
  }
  return acc;
}

// 16-element f16 dot (one 32B chunk), fp32 acc
__device__ __forceinline__ float dot16h(const _Float16* __restrict__ w,
                                        const _Float16* __restrict__ x) {
  u32x4 a0 = *(const u32x4*)w;
  u32x4 a1 = *(const u32x4*)(w + 8);
  u32x4 b0 = *(const u32x4*)x;
  u32x4 b1 = *(const u32x4*)(x + 8);
  float acc = 0.f;
  acc = dot2f(h2(a0.x), h2(b0.x), acc);
  acc = dot2f(h2(a0.y), h2(b0.y), acc);
  acc = dot2f(h2(a0.z), h2(b0.z), acc);
  acc = dot2f(h2(a0.w), h2(b0.w), acc);
  acc = dot2f(h2(a1.x), h2(b1.x), acc);
  acc = dot2f(h2(a1.y), h2(b1.y), acc);
  acc = dot2f(h2(a1.z), h2(b1.z), acc);
  acc = dot2f(h2(a1.w), h2(b1.w), acc);
  return acc;
}

__device__ __forceinline__ float fast_tanh(float x) {
  x = fminf(15.f, fmaxf(-15.f, x));
  float e = __expf(2.f * x);
  return 1.f - __fdividef(2.f, e + 1.f);
}
__device__ __forceinline__ float fast_sigmoid(float x) {
  x = fminf(30.f, fmaxf(-30.f, x));
  float e = __expf(-x);
  return __fdividef(1.f, 1.f + e);
}
__device__ __forceinline__ unsigned short f2bf(float f) {  // RNE fp32->bf16
  unsigned int u = __builtin_bit_cast(unsigned int, f);
  return (unsigned short)((u + 0x7FFFu + ((u >> 16) & 1u)) >> 16);
}

// fence-free per-batch barrier:
//  - release fetch_add (writeback-only on gfx95x, no L2 invalidate)
//  - relaxed agent spin (sc-bypass load sees the coherent point)
// All cross-WG data moves via agent-scope relaxed atomics, so no cache
// invalidation is ever required; L2 stays warm with the weight streams.
__device__ __forceinline__ void batch_barrier(int* __restrict__ ctr, int target) {
  __syncthreads();
  if (threadIdx.x == 0) {
    __hip_atomic_fetch_add(ctr, 1, __ATOMIC_RELEASE, AGENT);
    while (__hip_atomic_load(ctr, __ATOMIC_RELAXED, AGENT) < target)
      __builtin_amdgcn_s_sleep(1);
    asm volatile("" ::: "memory");
  }
  __syncthreads();
}

// ---------------- setup kernels ----------------

__global__ void conv_f16_kernel(const float* __restrict__ s, _Float16* __restrict__ d, int n) {
  int i = blockIdx.x * 256 + threadIdx.x;
  if (i < n) d[i] = (_Float16)s[i];
}

__global__ void conv_bf16_kernel(const float* __restrict__ s, unsigned short* __restrict__ d, int n) {
  int i = blockIdx.x * 256 + threadIdx.x;
  if (i < n) d[i] = f2bf(s[i]);
}

// enc_proj_w (256,512) -> wT (512,256)
__global__ void transpose_kernel(const float* __restrict__ w, float* __restrict__ wT) {
  int i = blockIdx.x * 256 + threadIdx.x;
  if (i < 256 * 512) { int h = i >> 9, dd = i & 511; wT[dd * 256 + h] = w[i]; }
}

// proj[b,s,h] = enc_proj_b[h] + sum_d enc[s,b,d]*W[h,d]; write kvT[b][h][s] (f16)
__global__ __launch_bounds__(256) void proj_kernel(const float* __restrict__ enc,
                                                   const float* __restrict__ wT,
                                                   const float* __restrict__ pb,
                                                   _Float16* __restrict__ kvT) {
  int gid = blockIdx.x * 256 + threadIdx.x;
  int h4 = gid & 63;
  int bs = gid >> 6;                 // = s*32 + b (matches enc layout)
  if (bs >= NTP1 * NB) return;
  int s = bs >> 5, b = bs & 31;
  const float* er = enc + (size_t)bs * 512;
  float a0 = 0.f, a1 = 0.f, a2 = 0.f, a3 = 0.f;
  for (int d = 0; d < 512; d += 4) {
    f32x4 e4 = *(const f32x4*)(er + d);
    f32x4 w0 = *(const f32x4*)(wT + (size_t)(d + 0) * 256 + h4 * 4);
    f32x4 w1 = *(const f32x4*)(wT + (size_t)(d + 1) * 256 + h4 * 4);
    f32x4 w2 = *(const f32x4*)(wT + (size_t)(d + 2) * 256 + h4 * 4);
    f32x4 w3 = *(const f32x4*)(wT + (size_t)(d + 3) * 256 + h4 * 4);
    a0 = fmaf(e4.x, w0.x, a0); a1 = fmaf(e4.x, w0.y, a1); a2 = fmaf(e4.x, w0.z, a2); a3 = fmaf(e4.x, w0.w, a3);
    a0 = fmaf(e4.y, w1.x, a0); a1 = fmaf(e4.y, w1.y, a1); a2 = fmaf(e4.y, w1.z, a2); a3 = fmaf(e4.y, w1.w, a3);
    a0 = fmaf(e4.z, w2.x, a0); a1 = fmaf(e4.z, w2.y, a1); a2 = fmaf(e4.z, w2.z, a2); a3 = fmaf(e4.z, w2.w, a3);
    a0 = fmaf(e4.w, w3.x, a0); a1 = fmaf(e4.w, w3.y, a1); a2 = fmaf(e4.w, w3.z, a2); a3 = fmaf(e4.w, w3.w, a3);
  }
  int h = h4 * 4;
  a0 += pb[h + 0]; a1 += pb[h + 1]; a2 += pb[h + 2]; a3 += pb[h + 3];
  size_t base = ((size_t)b * NH) * NL2 + s;
  kvT[base + (size_t)(h + 0) * NL2] = (_Float16)a0;
  kvT[base + (size_t)(h + 1) * NL2] = (_Float16)a1;
  kvT[base + (size_t)(h + 2) * NL2] = (_Float16)a2;
  kvT[base + (size_t)(h + 3) * NL2] = (_Float16)a3;
}

// kprojL[b][l][g] = sum_h kvT[b][h][l] * wk[g][h], for l < 257 (f16 out)
__global__ __launch_bounds__(256) void kproj0_kernel(const _Float16* __restrict__ kvT,
                                                     const float* __restrict__ wk,
                                                     _Float16* __restrict__ kprojL) {
  int b = blockIdx.x >> 3, gq = blockIdx.x & 7;
  __shared__ float wks[32][256];
  __shared__ float pk[32][8];
  int tid = threadIdx.x;
  for (int i = tid; i < 32 * 256; i += 256) {
    int g = i >> 8, h = i & 255;
    wks[g][h] = wk[(size_t)(gq * 32 + g) * 256 + h];
  }
  __syncthreads();
  {
    int l = tid;   // l in [0,256)
    float acc[32];
#pragma unroll
    for (int g = 0; g < 32; ++g) acc[g] = 0.f;
    for (int h = 0; h < 256; ++h) {
      float kvv = (float)kvT[((size_t)(b * NH + h)) * NL2 + l];
#pragma unroll
      for (int g = 0; g < 32; ++g) acc[g] = fmaf(kvv, wks[g][h], acc[g]);
    }
    for (int g = 0; g < 32; ++g)
      kprojL[((size_t)b * NL2 + l) * NH + gq * 32 + g] = (_Float16)acc[g];
  }
  // l == 256 handled cooperatively
  {
    int g = tid >> 3, hc = tid & 7;
    float acc = 0.f;
    for (int h = hc * 32; h < hc * 32 + 32; ++h)
      acc += (float)kvT[((size_t)(b * NH + h)) * NL2 + 256] * wks[g][h];
    pk[g][hc] = acc;
    __syncthreads();
    if (tid < 32) {
      float sv = 0.f;
      for (int c = 0; c < 8; ++c) sv += pk[tid][c];
      kprojL[((size_t)b * NL2 + 256) * NH + gq * 32 + tid] = (_Float16)sv;
    }
  }
}

// ---------------- cooperative scan: 8 WGs/batch, fence-free barriers, LDS kproj ----------------
// blockIdx: b = blk & 31, s = blk >> 5

__global__ __launch_bounds__(512) void scan_kernel(
    const int* __restrict__ x, const float* __restrict__ efs, const float* __restrict__ emb,
    const float* __restrict__ wv,
    const float* __restrict__ bih0, const float* __restrict__ bhh0,
    const float* __restrict__ bih1, const float* __restrict__ bhh1,
    const _Float16* __restrict__ wq16, const _Float16* __restrict__ wk16,
    const _Float16* __restrict__ wih0_16, const _Float16* __restrict__ whh0_16,
    const _Float16* __restrict__ wih1_16, const _Float16* __restrict__ whh1_16,
    _Float16* __restrict__ kvT, const _Float16* __restrict__ kprojL,
    float* __restrict__ q_g, float* __restrict__ scores_g, float* __restrict__ xin_gf,
    float* __restrict__ g0i_g, float* __restrict__ g0h_g,
    float* __restrict__ g1i_g, float* __restrict__ g1h_g,
    unsigned int* __restrict__ kstage,
    int* __restrict__ bars,
    unsigned short* __restrict__ outs_bf, float* __restrict__ attn_out) {
  __shared__ __align__(16) float h0s[256], h1s[256], qf[256], wvs[256];
  __shared__ __align__(16) float attnsP[16 * 34], red[16], scratch[544];
  __shared__ __align__(16) _Float16 h0h[256], h1h[256], xinh[512];
  __shared__ __align__(8) _Float16 kp_lds[64 * KPS];   // 64 l-rows x 256 g, stride 260

  int tid = threadIdx.x;
  int b = blockIdx.x & 31;
  int s = blockIdx.x >> 5;
  int* bar = bars + b * 32;

  // per-WG replicated state init
  if (tid < 256) {
    float h0v = efs[(size_t)(0 * NB + b) * NH + tid] + efs[(size_t)(1 * NB + b) * NH + tid];
    float h1v = efs[(size_t)(2 * NB + b) * NH + tid] + efs[(size_t)(3 * NB + b) * NH + tid];
    h0s[tid] = h0v; h0h[tid] = (_Float16)h0v;
    h1s[tid] = h1v; h1h[tid] = (_Float16)h1v;
    wvs[tid] = wv[tid];
  }
  // load own kproj slice (rows 64s..64s+64) into LDS (plain cached loads; prior kernel)
  {
    int lr = tid >> 3, ch = tid & 7;               // 64 rows x 8 chunks of 32 halves
    const _Float16* src = kprojL + ((size_t)b * NL2 + 64 * s + lr) * NH + ch * 32;
    _Float16* dst = kp_lds + lr * KPS + ch * 32;
#pragma unroll
    for (int k = 0; k < 32; k += 4)
      *(u32x2*)(dst + k) = *(const u32x2*)(src + k);
  }
  __syncthreads();

  for (int t = 0; t < NT; ++t) {
    int Lt = NTP1 + t;
    int tgt = 8 * (t + 1);
    // -- A: q slice rows [32s,32s+32): row=tid&31, k-chunk=tid>>5 (broadcast LDS reads)
    {
      int row = tid & 31, ch = tid >> 5;
      float p = dot16h(wq16 + (size_t)(32 * s + row) * 256 + ch * 16, h1h + ch * 16);
      scratch[ch * 33 + row] = p;
      if (tid < 32) {
        int tok = x[b * NT + t];
        astore(xin_gf + b * 512 + 256 + 32 * s + tid, emb[(size_t)tok * 256 + 32 * s + tid]);
      }
    }
    __syncthreads();
    if (tid < 32) {
      float a = 0.f;
#pragma unroll
      for (int c = 0; c < 16; ++c) a += scratch[c * 33 + tid];
      astore(q_g + b * 256 + 32 * s + tid, a);
    }
    batch_barrier(bar + 0, tgt);   // q, emb, and prev-step kproj staging visible
    // owner pulls staged kproj row (appended at t-1) into its LDS slice
    if (t > 0 && s == ((Lt - 1) >> 6)) {
      if (tid < 128) {
        unsigned int v = aloadu(kstage + b * 128 + tid);
        *(unsigned int*)(kp_lds + (Lt - 1 - 64 * s) * KPS + 2 * tid) = v;
      }
    }
    if (tid < 256) qf[tid] = aload(q_g + b * 256 + tid);
    __syncthreads();
    // -- B: scores: wave w=tid>>6 owns g-chunk [32w,32w+32), lane l'=tid&63 owns row l'
    {
      int w = tid >> 6, lp = tid & 63;
      int l = 64 * s + lp;
      float part = 0.f;
      if (l < Lt) {
        const _Float16* kp = kp_lds + lp * KPS + 32 * w;
        const float* qh = qf + 32 * w;
        const float* wh = wvs + 32 * w;
#pragma unroll
        for (int j = 0; j < 32; j += 4) {
          u32x2 k4 = *(const u32x2*)(kp + j);
          half2v pa = h2(k4.x), pb = h2(k4.y);
          part = fmaf(wh[j + 0], fast_tanh((float)pa[0] + qh[j + 0]), part);
          part = fmaf(wh[j + 1], fast_tanh((float)pa[1] + qh[j + 1]), part);
          part = fmaf(wh[j + 2], fast_tanh((float)pb[0] + qh[j + 2]), part);
          part = fmaf(wh[j + 3], fast_tanh((float)pb[1] + qh[j + 3]), part);
        }
      }
      scratch[w * 66 + lp] = part;
    }
    __syncthreads();
    if (tid < 64 && 64 * s + tid < Lt) {
      float a = 0.f;
#pragma unroll
      for (int w = 0; w < 8; ++w) a += scratch[w * 66 + tid];
      astore(scores_g + b * 512 + 64 * s + tid, a);
    }
    batch_barrier(bar + 1, tgt);   // all scores visible
    // -- C: softmax (replicated), padded-chunk LDS store, attn_out slice
    {
      float v = (tid < Lt) ? aload(scores_g + b * 512 + tid) : -3.0e38f;
      float m = v;
#pragma unroll
      for (int off = 32; off; off >>= 1) m = fmaxf(m, __shfl_xor(m, off, 64));
      if ((tid & 63) == 0) red[tid >> 6] = m;
      __syncthreads();
      float M = red[0];
#pragma unroll
      for (int i = 1; i < 8; ++i) M = fmaxf(M, red[i]);
      float e = (tid < Lt) ? __expf(v - M) : 0.f;
      float zz = e;
#pragma unroll
      for (int off = 32; off; off >>= 1) zz += __shfl_xor(zz, off, 64);
      if ((tid & 63) == 0) red[8 + (tid >> 6)] = zz;
      __syncthreads();
      float Z = red[8];
#pragma unroll
      for (int i = 1; i < 8; ++i) Z += red[8 + i];
      float a = __fdividef(e, Z);          // exact 0 for invalid slots
      attnsP[(tid >> 5) * 34 + (tid & 31)] = a;
      if ((tid >> 6) == s) attn_out[((size_t)(b * NT + t)) * NL2 + tid] = a;
    }
    __syncthreads();
    // -- D: context slice (h in [32s,32s+32)): sub=tid&15 owns l-chunk [32sub,32sub+32)
    {
      int h = 32 * s + (tid >> 4), sub = tid & 15;
      const _Float16* kvr = kvT + ((size_t)(b * NH + h)) * NL2 + sub * 32;
      const float* ar = attnsP + sub * 34;
      float a = 0.f;
#pragma unroll
      for (int k = 0; k < 32; k += 8) {
        u32x4 v8 = *(const u32x4*)(kvr + k);
        half2v c0 = h2(v8.x), c1 = h2(v8.y), c2 = h2(v8.z), c3 = h2(v8.w);
        f32x2 a0 = *(const f32x2*)(ar + k);
        f32x2 a1 = *(const f32x2*)(ar + k + 2);
        f32x2 a2 = *(const f32x2*)(ar + k + 4);
        f32x2 a3 = *(const f32x2*)(ar + k + 6);
        a = fmaf((float)c0[0], a0.x, a); a = fmaf((float)c0[1], a0.y, a);
        a = fmaf((float)c1[0], a1.x, a); a = fmaf((float)c1[1], a1.y, a);
        a = fmaf((float)c2[0], a2.x, a); a = fmaf((float)c2[1], a2.y, a);
        a = fmaf((float)c3[0], a3.x, a); a = fmaf((float)c3[1], a3.y, a);
      }
      a += __shfl_xor(a, 1); a += __shfl_xor(a, 2);
      a += __shfl_xor(a, 4); a += __shfl_xor(a, 8);
      if (sub == 0) astore(xin_gf + b * 512 + h, a);
    }
    batch_barrier(bar + 2, tgt);   // xin (ctx+emb) visible
    // -- E: GRU0 matvec slice (gate rows [96s,96s+96))
    if (tid < 512) xinh[tid] = (_Float16)aload(xin_gf + b * 512 + tid);
    __syncthreads();
    if (tid < 384) {
      int r = 96 * s + (tid >> 2), sub = tid & 3;
      float a = dotf16(wih0_16 + (size_t)r * 512 + sub * 128, xinh + sub * 128, 128, 0.f);
      a += __shfl_xor(a, 1); a += __shfl_xor(a, 2);
      if (sub == 0) astore(g0i_g + b * 768 + r, a + bih0[r]);
    } else if (tid < 480) {
      int r = 96 * s + (tid - 384);
      astore(g0h_g + b * 768 + r, dotf16(whh0_16 + (size_t)r * 256, h0h, 256, bhh0[r]));
    }
    batch_barrier(bar + 3, tgt);   // gates0 visible
    // -- F: h0 combine (replicated)
    if (tid < 256) {
      float ir = aload(g0i_g + b * 768 + tid),       hr = aload(g0h_g + b * 768 + tid);
      float iz = aload(g0i_g + b * 768 + 256 + tid), hz = aload(g0h_g + b * 768 + 256 + tid);
      float in_ = aload(g0i_g + b * 768 + 512 + tid), hn_ = aload(g0h_g + b * 768 + 512 + tid);
      float r_ = fast_sigmoid(ir + hr);
      float z_ = fast_sigmoid(iz + hz);
      float n_ = fast_tanh(in_ + r_ * hn_);
      float hv = (1.f - z_) * n_ + z_ * h0s[tid];
      h0s[tid] = hv; h0h[tid] = (_Float16)hv;
    }
    __syncthreads();
    // -- G: GRU1 matvec slice
    if (tid < 384) {
      int r = 96 * s + (tid >> 2), sub = tid & 3;
      float a = dotf16(wih1_16 + (size_t)r * 256 + sub * 64, h0h + sub * 64, 64, 0.f);
      a += __shfl_xor(a, 1); a += __shfl_xor(a, 2);
      if (sub == 0) astore(g1i_g + b * 768 + r, a + bih1[r]);
    } else if (tid < 480) {
      int r = 96 * s + (tid - 384);
      astore(g1h_g + b * 768 + r, dotf16(whh1_16 + (size_t)r * 256, h1h, 256, bhh1[r]));
    }
    batch_barrier(bar + 4, tgt);   // gates1 visible
    // -- H: h1 combine (replicated) + slice writes (outs, kv append: same-WG data)
    if (tid < 256) {
      float ir = aload(g1i_g + b * 768 + tid),       hr = aload(g1h_g + b * 768 + tid);
      float iz = aload(g1i_g + b * 768 + 256 + tid), hz = aload(g1h_g + b * 768 + 256 + tid);
      float in_ = aload(g1i_g + b * 768 + 512 + tid), hn_ = aload(g1h_g + b * 768 + 512 + tid);
      float r_ = fast_sigmoid(ir + hr);
      float z_ = fast_sigmoid(iz + hz);
      float n_ = fast_tanh(in_ + r_ * hn_);
      float hv = (1.f - z_) * n_ + z_ * h1s[tid];
      h1s[tid] = hv; h1h[tid] = (_Float16)hv;
      if ((tid >> 5) == s) {
        outs_bf[((size_t)(b * NT + t)) * NH + tid] = f2bf(hv);
        if (t < NT - 1) kvT[((size_t)(b * NH + tid)) * NL2 + NTP1 + t] = (_Float16)hv;
      }
    }
    __syncthreads();
    // -- I: kproj append g-slice [32s,32s+32) -> staging (read by owner after next bar0)
    if (t < NT - 1) {
      int row = tid & 31, ch = tid >> 5;
      float p = dot16h(wk16 + (size_t)(32 * s + row) * 256 + ch * 16, h1h + ch * 16);
      scratch[ch * 33 + row] = p;
      __syncthreads();
      if (tid < 32) {
        float a = 0.f;
#pragma unroll
        for (int c = 0; c < 16; ++c) a += scratch[c * 33 + tid];
        unsigned short lo = __builtin_bit_cast(unsigned short, (_Float16)a);
        float an = __shfl_down(a, 1);
        unsigned short hi = __builtin_bit_cast(unsigned short, (_Float16)an);
        if ((tid & 1) == 0)
          astoreu(kstage + b * 128 + 16 * s + (tid >> 1),
                  (unsigned int)lo | ((unsigned int)hi << 16));
      }
      __syncthreads();
    }
  }
}

// ---------------- logits GEMM: C(8192x32000) = A(8192x256) * B^T + bias, bf16 MFMA ----------------

__global__ __launch_bounds__(256) void logits_gemm(const unsigned short* __restrict__ A,
                                                   const unsigned short* __restrict__ Bw,
                                                   const float* __restrict__ bias,
                                                   float* __restrict__ C) {
  __shared__ unsigned short As[128][88];
  __shared__ unsigned short Bs[128][88];
  int tid = threadIdx.x;
  int nt = blockIdx.x % 250, mt = blockIdx.x / 250;
  int m0 = mt * 128, n0 = nt * 128;
  int lane = tid & 63, w = tid >> 6;
  int wm = w & 1, wn = w >> 1;
  f32x4 acc[4][4];
#pragma unroll
  for (int m = 0; m < 4; ++m)
#pragma unroll
    for (int n = 0; n < 4; ++n) acc[m][n] = (f32x4)0.0f;

  int r0 = tid >> 3;
  int c0 = (tid & 7) * 8;
  for (int kt = 0; kt < 4; ++kt) {
    __syncthreads();
#pragma unroll
    for (int it = 0; it < 4; ++it) {
      int row = it * 32 + r0;
      u32x4 va = *(const u32x4*)(A + (size_t)(m0 + row) * 256 + kt * 64 + c0);
      u32x4 vb = *(const u32x4*)(Bw + (size_t)(n0 + row) * 256 + kt * 64 + c0);
      *(u32x4*)(&As[row][c0]) = va;
      *(u32x4*)(&Bs[row][c0]) = vb;
    }
    __syncthreads();
#pragma unroll
    for (int ks = 0; ks < 2; ++ks) {
      s16x8 af[4], bf[4];
#pragma unroll
      for (int m = 0; m < 4; ++m)
        af[m] = *(const s16x8*)(&As[wm * 64 + m * 16 + (lane & 15)][ks * 32 + (lane >> 4) * 8]);
#pragma unroll
      for (int n = 0; n < 4; ++n)
        bf[n] = *(const s16x8*)(&Bs[wn * 64 + n * 16 + (lane & 15)][ks * 32 + (lane >> 4) * 8]);
#pragma unroll
      for (int m = 0; m < 4; ++m)
#pragma unroll
        for (int n = 0; n < 4; ++n)
          acc[m][n] = __builtin_amdgcn_mfma_f32_16x16x32_bf16(af[m], bf[n], acc[m][n], 0, 0, 0);
    }
  }
#pragma unroll
  for (int n = 0; n < 4; ++n) {
    int col = n0 + wn * 64 + n * 16 + (lane & 15);
    float bv = bias[col];
#pragma unroll
    for (int m = 0; m < 4; ++m) {
      int rowb = m0 + wm * 64 + m * 16 + (lane >> 4) * 4;
#pragma unroll
      for (int r = 0; r < 4; ++r)
        C[(size_t)(rowb + r) * NV + col] = acc[m][n][r] + bv;
    }
  }
}

// ---------------- host launch ----------------

extern "C" void kernel_launch(void* const* d_in, const int* in_sizes, int n_in,
                              void* d_out, int out_size, void* d_ws, size_t ws_size,
                              hipStream_t stream) {
  const int*   x    = (const int*)d_in[0];
  const float* enc  = (const float*)d_in[1];
  const float* efs  = (const float*)d_in[2];
  const float* emb  = (const float*)d_in[3];
  const float* epw  = (const float*)d_in[4];
  const float* epb  = (const float*)d_in[5];
  const float* wq   = (const float*)d_in[6];
  const float* wk   = (const float*)d_in[7];
  const float* wv   = (const float*)d_in[8];
  const float* wih0 = (const float*)d_in[9];
  const float* whh0 = (const float*)d_in[10];
  const float* bih0 = (const float*)d_in[11];
  const float* bhh0 = (const float*)d_in[12];
  const float* wih1 = (const float*)d_in[13];
  const float* whh1 = (const float*)d_in[14];
  const float* bih1 = (const float*)d_in[15];
  const float* bhh1 = (const float*)d_in[16];
  const float* dw   = (const float*)d_in[17];
  const float* db   = (const float*)d_in[18];

  // workspace layout (bytes); f16 weights alias dwbf16 region (conv_bf16 runs AFTER scan)
  const size_t o_dwbf   = 0;                        // 16,384,000
  const size_t o_wT     = o_dwbf + 16384000;        // 524,288
  const size_t o_kvT    = o_wT + 524288;            // 8,388,608 (f16)
  const size_t o_kproj  = o_kvT + 8388608;          // 8,388,608 (f16)
  const size_t o_outs   = o_kproj + 8388608;        // 4,194,304 (bf16)
  const size_t o_qg     = o_outs + 4194304;         // 32*256*4 = 32,768
  const size_t o_scores = o_qg + 32768;             // 32*512*4 = 65,536
  const size_t o_xinf   = o_scores + 65536;         // 32*512*4 = 65,536
  const size_t o_g0i    = o_xinf + 65536;           // 32*768*4 = 98,304
  const size_t o_g0h    = o_g0i + 98304;            // 98,304
  const size_t o_g1i    = o_g0h + 98304;            // 98,304
  const size_t o_g1h    = o_g1i + 98304;            // 98,304
  const size_t o_kst    = o_g1h + 98304;            // 32*128*4 = 16,384
  const size_t o_bar    = o_kst + 16384;            // 32*32*4  = 4,096
  const size_t need     = o_bar + 4096;             // ~38.5 MB
  if (ws_size < need) return;  // fail visibly rather than corrupt

  char* ws = (char*)d_ws;
  unsigned short* dwbf16 = (unsigned short*)(ws + o_dwbf);
  _Float16* wq16    = (_Float16*)(ws + o_dwbf);            // 131,072 B
  _Float16* wk16    = (_Float16*)(ws + o_dwbf + 131072);   // 131,072 B
  _Float16* wih0_16 = (_Float16*)(ws + o_dwbf + 262144);   // 786,432 B
  _Float16* whh0_16 = (_Float16*)(ws + o_dwbf + 1048576);  // 393,216 B
  _Float16* wih1_16 = (_Float16*)(ws + o_dwbf + 1441792);  // 393,216 B
  _Float16* whh1_16 = (_Float16*)(ws + o_dwbf + 1835008);  // 393,216 B
  float* wT          = (float*)(ws + o_wT);
  _Float16* kvT      = (_Float16*)(ws + o_kvT);
  _Float16* kprojL   = (_Float16*)(ws + o_kproj);
  unsigned short* outs_bf = (unsigned short*)(ws + o_outs);
  float* q_g         = (float*)(ws + o_qg);
  float* scores_g    = (float*)(ws + o_scores);
  float* xin_gf      = (float*)(ws + o_xinf);
  float* g0i_g       = (float*)(ws + o_g0i);
  float* g0h_g       = (float*)(ws + o_g0h);
  float* g1i_g       = (float*)(ws + o_g1i);
  float* g1h_g       = (float*)(ws + o_g1h);
  unsigned int* kstage = (unsigned int*)(ws + o_kst);
  int* bars          = (int*)(ws + o_bar);

  float* logits = (float*)d_out;
  float* attn_out = logits + (size_t)NB * NT * NV;

  // zero-init KV buffers (invalid slots must be finite zeros) and barrier counters
  hipMemsetAsync(ws + o_kvT, 0, 2 * 8388608, stream);
  hipMemsetAsync(ws + o_bar, 0, 4096, stream);

  // f16 weight conversions (into the region later overwritten by dwbf16)
  conv_f16_kernel<<<(65536 + 255) / 256, 256, 0, stream>>>(wq, wq16, 65536);
  conv_f16_kernel<<<(65536 + 255) / 256, 256, 0, stream>>>(wk, wk16, 65536);
  conv_f16_kernel<<<(393216 + 255) / 256, 256, 0, stream>>>(wih0, wih0_16, 393216);
  conv_f16_kernel<<<(196608 + 255) / 256, 256, 0, stream>>>(whh0, whh0_16, 196608);
  conv_f16_kernel<<<(196608 + 255) / 256, 256, 0, stream>>>(wih1, wih1_16, 196608);
  conv_f16_kernel<<<(196608 + 255) / 256, 256, 0, stream>>>(whh1, whh1_16, 196608);
  transpose_kernel<<<(131072 + 255) / 256, 256, 0, stream>>>(epw, wT);

  // encoder projection -> kvT (f16), then key projections -> kprojL [b][l][g] (f16)
  proj_kernel<<<(NTP1 * NB * 64) / 256, 256, 0, stream>>>(enc, wT, epb, kvT);
  kproj0_kernel<<<NB * 8, 256, 0, stream>>>(kvT, wk, kprojL);

  // cooperative scan: 256 WGs (8 per batch), 512 threads each — 1 WG/CU co-resident
  scan_kernel<<<256, 512, 0, stream>>>(x, efs, emb, wv, bih0, bhh0, bih1, bhh1,
                                       wq16, wk16, wih0_16, whh0_16, wih1_16, whh1_16,
                                       kvT, kprojL,
                                       q_g, scores_g, xin_gf,
                                       g0i_g, g0h_g, g1i_g, g1h_g, kstage, bars,
                                       outs_bf, attn_out);

  // now safe to overwrite the f16-weight region with bf16 dense_w
  conv_bf16_kernel<<<(8192000 + 255) / 256, 256, 0, stream>>>(dw, dwbf16, 8192000);

  // final big GEMM: logits
  logits_gemm<<<(NB * NT / 128) * (NV / 128), 256, 0, stream>>>(outs_bf, dwbf16, db, logits);
}

// Round 7
// 7128.826 us; speedup vs baseline: 5.8744x; 1.1398x over previous
//
#include <hip/hip_runtime.h>
#include <hip/hip_bf16.h>
#include <hip/hip_fp16.h>

// Problem sizes
#define NB 32
#define NT 256
#define NH 256
#define NV 32000
#define NL2 512     // fixed KV length = 2T
#define NTP1 257    // T+1

typedef unsigned int u32x4 __attribute__((ext_vector_type(4)));
typedef unsigned int u32x2 __attribute__((ext_vector_type(2)));
typedef short s16x8 __attribute__((ext_vector_type(8)));
typedef float f32x4 __attribute__((ext_vector_type(4)));
typedef _Float16 half2v __attribute__((ext_vector_type(2)));

#define AGENT __HIP_MEMORY_SCOPE_AGENT
__device__ __forceinline__ float aload(const float* p) {
  return __hip_atomic_load((float*)p, __ATOMIC_RELAXED, AGENT);
}
__device__ __forceinline__ void astore(float* p, float v) {
  __hip_atomic_store(p, v, __ATOMIC_RELAXED, AGENT);
}

__device__ __forceinline__ float dot2f(half2v a, half2v b, float c) {
#if __has_builtin(__builtin_amdgcn_fdot2)
  return __builtin_amdgcn_fdot2(a, b, c, false);
#else
  return c + (float)a[0] * (float)b[0] + (float)a[1] * (float)b[1];
#endif
}
__device__ __forceinline__ half2v h2(unsigned int u) { return __builtin_bit_cast(half2v, u); }

// 16-element f16 dot (one 32B chunk), fp32 acc
__device__ __forceinline__ float dot16h(const _Float16* __restrict__ w,
                                        const _Float16* __restrict__ x) {
  u32x4 a0 = *(const u32x4*)w;
  u32x4 a1 = *(const u32x4*)(w + 8);
  u32x4 b0 = *(const u32x4*)x;
  u32x4 b1 = *(const u32x4*)(x + 8);
  float acc = 0.f;
  acc = dot2f(h2(a0.x), h2(b0.x), acc);
  acc = dot2f(h2(a0.y), h2(b0.y), acc);
  acc = dot2f(h2(a0.z), h2(b0.z), acc);
  acc = dot2f(h2(a0.w), h2(b0.w), acc);
  acc = dot2f(h2(a1.x), h2(b1.x), acc);
  acc = dot2f(h2(a1.y), h2(b1.y), acc);
  acc = dot2f(h2(a1.z), h2(b1.z), acc);
  acc = dot2f(h2(a1.w), h2(b1.w), acc);
  return acc;
}

__device__ __forceinline__ float fast_tanh(float x) {
  x = fminf(15.f, fmaxf(-15.f, x));
  float e = __expf(2.f * x);
  return 1.f - __fdividef(2.f, e + 1.f);
}
__device__ __forceinline__ float fast_sigmoid(float x) {
  x = fminf(30.f, fmaxf(-30.f, x));
  float e = __expf(-x);
  return __fdividef(1.f, 1.f + e);
}
__device__ __forceinline__ unsigned short f2bf(float f) {  // RNE fp32->bf16
  unsigned int u = __builtin_bit_cast(unsigned int, f);
  return (unsigned short)((u + 0x7FFFu + ((u >> 16) & 1u)) >> 16);
}

// fence-free per-batch barrier (proven in R6): release add, relaxed agent spin
__device__ __forceinline__ void batch_barrier(int* __restrict__ ctr, int target) {
  __syncthreads();
  if (threadIdx.x == 0) {
    __hip_atomic_fetch_add(ctr, 1, __ATOMIC_RELEASE, AGENT);
    while (__hip_atomic_load(ctr, __ATOMIC_RELAXED, AGENT) < target)
      __builtin_amdgcn_s_sleep(1);
    asm volatile("" ::: "memory");
  }
  __syncthreads();
}

// ---------------- setup kernels ----------------

__global__ void conv_f16_kernel(const float* __restrict__ s, _Float16* __restrict__ d, int n) {
  int i = blockIdx.x * 256 + threadIdx.x;
  if (i < n) d[i] = (_Float16)s[i];
}

__global__ void conv_bf16_kernel(const float* __restrict__ s, unsigned short* __restrict__ d, int n) {
  int i = blockIdx.x * 256 + threadIdx.x;
  if (i < n) d[i] = f2bf(s[i]);
}

// pack-transpose: out[k2][r] = f16pair(w[r][2k2], w[r][2k2+1]); coalesced writes
__global__ void packT_kernel(const float* __restrict__ w, unsigned int* __restrict__ out,
                             int R, int K) {
  int gid = blockIdx.x * 256 + threadIdx.x;
  int K2 = K >> 1;
  if (gid >= R * K2) return;
  int k2 = gid / R, r = gid - k2 * R;
  unsigned short ua = __builtin_bit_cast(unsigned short, (_Float16)w[(size_t)r * K + 2 * k2]);
  unsigned short ub = __builtin_bit_cast(unsigned short, (_Float16)w[(size_t)r * K + 2 * k2 + 1]);
  out[(size_t)k2 * R + r] = (unsigned int)ua | ((unsigned int)ub << 16);
}

// enc_proj_w (256,512) -> wT (512,256)
__global__ void transpose_kernel(const float* __restrict__ w, float* __restrict__ wT) {
  int i = blockIdx.x * 256 + threadIdx.x;
  if (i < 256 * 512) { int h = i >> 9, dd = i & 511; wT[dd * 256 + h] = w[i]; }
}

// proj[b,s,h] = enc_proj_b[h] + sum_d enc[s,b,d]*W[h,d]; write kvL[b][l=s][h] (f16)
__global__ __launch_bounds__(256) void proj_kernel(const float* __restrict__ enc,
                                                   const float* __restrict__ wT,
                                                   const float* __restrict__ pb,
                                                   _Float16* __restrict__ kvL) {
  int gid = blockIdx.x * 256 + threadIdx.x;
  int h4 = gid & 63;
  int bs = gid >> 6;                 // = s*32 + b (matches enc layout)
  if (bs >= NTP1 * NB) return;
  int s = bs >> 5, b = bs & 31;
  const float* er = enc + (size_t)bs * 512;
  float a0 = 0.f, a1 = 0.f, a2 = 0.f, a3 = 0.f;
  for (int d = 0; d < 512; d += 4) {
    f32x4 e4 = *(const f32x4*)(er + d);
    f32x4 w0 = *(const f32x4*)(wT + (size_t)(d + 0) * 256 + h4 * 4);
    f32x4 w1 = *(const f32x4*)(wT + (size_t)(d + 1) * 256 + h4 * 4);
    f32x4 w2 = *(const f32x4*)(wT + (size_t)(d + 2) * 256 + h4 * 4);
    f32x4 w3 = *(const f32x4*)(wT + (size_t)(d + 3) * 256 + h4 * 4);
    a0 = fmaf(e4.x, w0.x, a0); a1 = fmaf(e4.x, w0.y, a1); a2 = fmaf(e4.x, w0.z, a2); a3 = fmaf(e4.x, w0.w, a3);
    a0 = fmaf(e4.y, w1.x, a0); a1 = fmaf(e4.y, w1.y, a1); a2 = fmaf(e4.y, w1.z, a2); a3 = fmaf(e4.y, w1.w, a3);
    a0 = fmaf(e4.z, w2.x, a0); a1 = fmaf(e4.z, w2.y, a1); a2 = fmaf(e4.z, w2.z, a2); a3 = fmaf(e4.z, w2.w, a3);
    a0 = fmaf(e4.w, w3.x, a0); a1 = fmaf(e4.w, w3.y, a1); a2 = fmaf(e4.w, w3.z, a2); a3 = fmaf(e4.w, w3.w, a3);
  }
  int h = h4 * 4;
  a0 += pb[h + 0]; a1 += pb[h + 1]; a2 += pb[h + 2]; a3 += pb[h + 3];
  _Float16* dst = kvL + ((size_t)b * 512 + s) * 256 + h;
  dst[0] = (_Float16)a0; dst[1] = (_Float16)a1;
  dst[2] = (_Float16)a2; dst[3] = (_Float16)a3;
}

// kprojL[b][l][g] = sum_h kvL[b][l][h] * wk[g][h], for l < 257 (f16 out)
__global__ __launch_bounds__(256) void kproj0_kernel(const _Float16* __restrict__ kvL,
                                                     const float* __restrict__ wk,
                                                     _Float16* __restrict__ kprojL) {
  int b = blockIdx.x >> 3, gq = blockIdx.x & 7;
  __shared__ float wks[32][256];
  __shared__ float pk[32][8];
  int tid = threadIdx.x;
  for (int i = tid; i < 32 * 256; i += 256) {
    int g = i >> 8, h = i & 255;
    wks[g][h] = wk[(size_t)(gq * 32 + g) * 256 + h];
  }
  __syncthreads();
  {
    int l = tid;   // l in [0,256)
    float acc[32];
#pragma unroll
    for (int g = 0; g < 32; ++g) acc[g] = 0.f;
    for (int h = 0; h < 256; ++h) {
      float kvv = (float)kvL[((size_t)b * 512 + l) * 256 + h];
#pragma unroll
      for (int g = 0; g < 32; ++g) acc[g] = fmaf(kvv, wks[g][h], acc[g]);
    }
    for (int g = 0; g < 32; ++g)
      kprojL[((size_t)b * NL2 + l) * NH + gq * 32 + g] = (_Float16)acc[g];
  }
  // l == 256 handled cooperatively
  {
    int g = tid >> 3, hc = tid & 7;
    float acc = 0.f;
    for (int h = hc * 32; h < hc * 32 + 32; ++h)
      acc += (float)kvL[((size_t)b * 512 + 256) * 256 + h] * wks[g][h];
    pk[g][hc] = acc;
    __syncthreads();
    if (tid < 32) {
      float sv = 0.f;
      for (int c = 0; c < 8; ++c) sv += pk[tid][c];
      kprojL[((size_t)b * NL2 + 256) * NH + gq * 32 + tid] = (_Float16)sv;
    }
  }
}

// ---------------- cooperative scan: 8 WGs/batch, 3 exchanges/step, LDS-private kv/kproj ----
// blockIdx: b = blk & 31, s = blk >> 5. Slices: g/h-slice [32s,32s+32), k2-slice [16s,16s+16).

__global__ __launch_bounds__(512) void scan_kernel(
    const int* __restrict__ x, const float* __restrict__ efs, const float* __restrict__ emb,
    const float* __restrict__ wv,
    const float* __restrict__ bih0, const float* __restrict__ bhh0,
    const float* __restrict__ bih1, const float* __restrict__ bhh1,
    const _Float16* __restrict__ wq16, const _Float16* __restrict__ wk16,
    const unsigned int* __restrict__ wih0T, const unsigned int* __restrict__ whh0T,
    const unsigned int* __restrict__ wih1T, const unsigned int* __restrict__ whh1T,
    const unsigned int* __restrict__ kvL_u, const unsigned int* __restrict__ kprojL_u,
    float* __restrict__ spart, float* __restrict__ vec0, float* __restrict__ vec1,
    int* __restrict__ bars,
    unsigned short* __restrict__ outs_bf, float* __restrict__ attn_out) {
  __shared__ __align__(16) unsigned int kp_u[512 * 17];  // kproj slice: f16[512][34], 16 u32 used
  __shared__ __align__(16) unsigned int kv_u[512 * 19];  // kv slice: pairs [512][19], 16 used
  __shared__ __align__(16) float att[512], gsum[1024];
  __shared__ __align__(16) float h0s[256], h1s[256];
  __shared__ __align__(16) float scr[544], scr2[32 * 35];
  __shared__ __align__(16) float qs[32], wvs[32], red[16];
  __shared__ __align__(16) _Float16 h0h[256], h1h[256], xinh[64];

  int tid = threadIdx.x;
  int b = blockIdx.x & 31;
  int s = blockIdx.x >> 5;
  int* bar = bars + b * 32;

  // replicated state init
  if (tid < 256) {
    float h0v = efs[(size_t)(0 * NB + b) * NH + tid] + efs[(size_t)(1 * NB + b) * NH + tid];
    float h1v = efs[(size_t)(2 * NB + b) * NH + tid] + efs[(size_t)(3 * NB + b) * NH + tid];
    h0s[tid] = h0v; h0h[tid] = (_Float16)h0v;
    h1s[tid] = h1v; h1h[tid] = (_Float16)h1v;
  }
  if (tid < 32) wvs[tid] = wv[32 * s + tid];
  // init private kp/kv LDS slices (cols = local u32 pairs of the 32-wide slice)
  for (int idx = tid; idx < 257 * 16; idx += 512) {
    int l = idx >> 4, c = idx & 15;
    kp_u[l * 17 + c] = kprojL_u[((size_t)b * 512 + l) * 128 + 16 * s + c];
    kv_u[l * 19 + c] = kvL_u[((size_t)b * 512 + l) * 128 + 16 * s + c];
  }
  for (int idx = tid; idx < 255 * 16; idx += 512) {
    int l = 257 + (idx >> 4), c = idx & 15;
    kp_u[l * 17 + c] = 0u;
    kv_u[l * 19 + c] = 0u;
  }
  __syncthreads();

  for (int t = 0; t < NT; ++t) {
    int Lt = NTP1 + t;
    int tgt = 8 * (t + 1);
    // -- P1: q slice (local; h1 replicated) + emb slice gather
    {
      int row = tid & 31, ch = tid >> 5;
      scr[ch * 33 + row] = dot16h(wq16 + (size_t)(32 * s + row) * 256 + ch * 16, h1h + ch * 16);
      if (tid >= 480) {
        int j = tid - 480;
        int tok = x[b * NT + t];
        xinh[32 + j] = (_Float16)emb[(size_t)tok * 256 + 32 * s + j];
      }
    }
    __syncthreads();
    if (tid < 32) {
      float a = 0.f;
#pragma unroll
      for (int c = 0; c < 16; ++c) a += scr[c * 33 + tid];
      qs[tid] = a;
    }
    __syncthreads();
    // -- P1b: score partials over local g-chunk, l = tid
    {
      float acc = 0.f;
      if (tid < Lt) {
        const unsigned int* kr = kp_u + tid * 17;
#pragma unroll 4
        for (int g2 = 0; g2 < 16; ++g2) {
          half2v kp2 = h2(kr[g2]);
          acc = fmaf(wvs[2 * g2 + 0], fast_tanh((float)kp2[0] + qs[2 * g2 + 0]), acc);
          acc = fmaf(wvs[2 * g2 + 1], fast_tanh((float)kp2[1] + qs[2 * g2 + 1]), acc);
        }
      }
      astore(spart + ((size_t)(b * 8 + s)) * 512 + tid, acc);
    }
    batch_barrier(bar + 0, tgt);   // E1: score partials
    // -- softmax (replicated)
    {
      float sum = 0.f;
#pragma unroll
      for (int sp = 0; sp < 8; ++sp) sum += aload(spart + ((size_t)(b * 8 + sp)) * 512 + tid);
      float v = (tid < Lt) ? sum : -3.0e38f;
      float m = v;
#pragma unroll
      for (int off = 32; off; off >>= 1) m = fmaxf(m, __shfl_xor(m, off, 64));
      if ((tid & 63) == 0) red[tid >> 6] = m;
      __syncthreads();
      float M = red[0];
#pragma unroll
      for (int i = 1; i < 8; ++i) M = fmaxf(M, red[i]);
      float e = (tid < Lt) ? __expf(v - M) : 0.f;
      float zz = e;
#pragma unroll
      for (int off = 32; off; off >>= 1) zz += __shfl_xor(zz, off, 64);
      if ((tid & 63) == 0) red[8 + (tid >> 6)] = zz;
      __syncthreads();
      float Z = red[8];
#pragma unroll
      for (int i = 1; i < 8; ++i) Z += red[8 + i];
      float a = __fdividef(e, Z);          // exact 0 for invalid slots
      att[tid] = a;
      if ((tid >> 6) == s) attn_out[((size_t)(b * NT + t)) * NL2 + tid] = a;
    }
    __syncthreads();
    // -- ctx slice from private kv (h' = 2hh,2hh+1 local)
    {
      int c = tid >> 4, hh = tid & 15;
      float aA = 0.f, aB = 0.f;
#pragma unroll
      for (int j = 0; j < 16; ++j) {
        int l = 16 * c + j;
        half2v kv2 = h2(kv_u[l * 19 + hh]);
        float av = att[l];
        aA = fmaf((float)kv2[0], av, aA);
        aB = fmaf((float)kv2[1], av, aB);
      }
      scr2[c * 35 + 2 * hh] = aA;
      scr2[c * 35 + 2 * hh + 1] = aB;
    }
    __syncthreads();
    if (tid < 32) {
      float a = 0.f;
#pragma unroll
      for (int c = 0; c < 32; ++c) a += scr2[c * 35 + tid];
      xinh[tid] = (_Float16)a;             // ctx local slice = gi0's k-slice
    }
    __syncthreads();
    // -- gi0+gh0 k-sliced partials (transposed packed weights, coalesced)
    {
      const unsigned int* xu = (const unsigned int*)xinh;   // [0..16) ctx pairs, [16..32) emb pairs
      const unsigned int* h0u = (const unsigned int*)h0h;
      float accA = 0.f, accI = 0.f, accH = 0.f;
      bool dual = (tid < 256);
#pragma unroll 2
      for (int i = 0; i < 16; ++i) {
        unsigned int xc = xu[i], xe = xu[16 + i];
        const unsigned int* wc = wih0T + (size_t)(16 * s + i) * 768;
        const unsigned int* we = wih0T + (size_t)(128 + 16 * s + i) * 768;
        accA = dot2f(h2(wc[tid]), h2(xc), accA);
        accA = dot2f(h2(we[tid]), h2(xe), accA);
        if (dual) {
          accI = dot2f(h2(wc[512 + tid]), h2(xc), accI);
          accI = dot2f(h2(we[512 + tid]), h2(xe), accI);
        }
      }
#pragma unroll 2
      for (int i = 0; i < 16; ++i) {
        unsigned int hv = h0u[16 * s + i];
        const unsigned int* wr = whh0T + (size_t)(16 * s + i) * 768;
        accA = dot2f(h2(wr[tid]), h2(hv), accA);
        if (dual) accH = dot2f(h2(wr[512 + tid]), h2(hv), accH);
      }
      float* vb = vec0 + (size_t)(b * 8 + s) * 1024;
      astore(vb + tid, accA);
      if (dual) { astore(vb + 512 + tid, accI); astore(vb + 768 + tid, accH); }
    }
    batch_barrier(bar + 1, tgt);   // E2: GRU0 gate partials
    // -- combine h0 (replicated)
    {
      float t0 = 0.f, t1 = 0.f;
#pragma unroll
      for (int sp = 0; sp < 8; ++sp) {
        const float* vb = vec0 + (size_t)(b * 8 + sp) * 1024;
        t0 += aload(vb + tid);
        t1 += aload(vb + 512 + tid);
      }
      gsum[tid] = t0; gsum[512 + tid] = t1;
    }
    __syncthreads();
    if (tid < 256) {
      float rr = fast_sigmoid(gsum[tid] + bih0[tid] + bhh0[tid]);
      float zz = fast_sigmoid(gsum[256 + tid] + bih0[256 + tid] + bhh0[256 + tid]);
      float nn = fast_tanh(gsum[512 + tid] + bih0[512 + tid] + rr * (gsum[768 + tid] + bhh0[512 + tid]));
      float hv = (1.f - zz) * nn + zz * h0s[tid];
      h0s[tid] = hv; h0h[tid] = (_Float16)hv;
    }
    __syncthreads();
    // -- gi1+gh1 k-sliced partials (h0 new, h1 old — both replicated/local)
    {
      const unsigned int* h0u = (const unsigned int*)h0h;
      const unsigned int* h1u = (const unsigned int*)h1h;
      float accA = 0.f, accI = 0.f, accH = 0.f;
      bool dual = (tid < 256);
#pragma unroll 2
      for (int i = 0; i < 16; ++i) {
        unsigned int xv = h0u[16 * s + i];
        unsigned int hv = h1u[16 * s + i];
        const unsigned int* wi = wih1T + (size_t)(16 * s + i) * 768;
        const unsigned int* wh = whh1T + (size_t)(16 * s + i) * 768;
        accA = dot2f(h2(wi[tid]), h2(xv), accA);
        accA = dot2f(h2(wh[tid]), h2(hv), accA);
        if (dual) {
          accI = dot2f(h2(wi[512 + tid]), h2(xv), accI);
          accH = dot2f(h2(wh[512 + tid]), h2(hv), accH);
        }
      }
      float* vb = vec1 + (size_t)(b * 8 + s) * 1024;
      astore(vb + tid, accA);
      if (dual) { astore(vb + 512 + tid, accI); astore(vb + 768 + tid, accH); }
    }
    batch_barrier(bar + 2, tgt);   // E3: GRU1 gate partials
    // -- combine h1 (replicated) + outs slice
    {
      float t0 = 0.f, t1 = 0.f;
#pragma unroll
      for (int sp = 0; sp < 8; ++sp) {
        const float* vb = vec1 + (size_t)(b * 8 + sp) * 1024;
        t0 += aload(vb + tid);
        t1 += aload(vb + 512 + tid);
      }
      gsum[tid] = t0; gsum[512 + tid] = t1;
    }
    __syncthreads();
    if (tid < 256) {
      float rr = fast_sigmoid(gsum[tid] + bih1[tid] + bhh1[tid]);
      float zz = fast_sigmoid(gsum[256 + tid] + bih1[256 + tid] + bhh1[256 + tid]);
      float nn = fast_tanh(gsum[512 + tid] + bih1[512 + tid] + rr * (gsum[768 + tid] + bhh1[512 + tid]));
      float hv = (1.f - zz) * nn + zz * h1s[tid];
      h1s[tid] = hv; h1h[tid] = (_Float16)hv;
      if ((tid >> 5) == s) outs_bf[((size_t)(b * NT + t)) * NH + tid] = f2bf(hv);
    }
    __syncthreads();
    // -- appends (all local to this WG's LDS slices)
    if (t < NT - 1) {
      int pos = NTP1 + t;
      if (tid < 16) {
        unsigned short lo = __builtin_bit_cast(unsigned short, h1h[32 * s + 2 * tid]);
        unsigned short hi = __builtin_bit_cast(unsigned short, h1h[32 * s + 2 * tid + 1]);
        kv_u[pos * 19 + tid] = (unsigned int)lo | ((unsigned int)hi << 16);
      }
      {
        int row = tid & 31, ch = tid >> 5;
        scr[ch * 33 + row] = dot16h(wk16 + (size_t)(32 * s + row) * 256 + ch * 16, h1h + ch * 16);
      }
      __syncthreads();
      if (tid < 32) {
        float a = 0.f;
#pragma unroll
        for (int c = 0; c < 16; ++c) a += scr[c * 33 + tid];
        ((_Float16*)kp_u)[pos * 34 + tid] = (_Float16)a;
      }
      __syncthreads();
    }
  }
}

// ---------------- logits GEMM: C(8192x32000) = A(8192x256) * B^T + bias, bf16 MFMA ----------------

__global__ __launch_bounds__(256) void logits_gemm(const unsigned short* __restrict__ A,
                                                   const unsigned short* __restrict__ Bw,
                                                   const float* __restrict__ bias,
                                                   float* __restrict__ C) {
  __shared__ unsigned short As[128][88];
  __shared__ unsigned short Bs[128][88];
  int tid = threadIdx.x;
  int nt = blockIdx.x % 250, mt = blockIdx.x / 250;
  int m0 = mt * 128, n0 = nt * 128;
  int lane = tid & 63, w = tid >> 6;
  int wm = w & 1, wn = w >> 1;
  f32x4 acc[4][4];
#pragma unroll
  for (int m = 0; m < 4; ++m)
#pragma unroll
    for (int n = 0; n < 4; ++n) acc[m][n] = (f32x4)0.0f;

  int r0 = tid >> 3;
  int c0 = (tid & 7) * 8;
  for (int kt = 0; kt < 4; ++kt) {
    __syncthreads();
#pragma unroll
    for (int it = 0; it < 4; ++it) {
      int row = it * 32 + r0;
      u32x4 va = *(const u32x4*)(A + (size_t)(m0 + row) * 256 + kt * 64 + c0);
      u32x4 vb = *(const u32x4*)(Bw + (size_t)(n0 + row) * 256 + kt * 64 + c0);
      *(u32x4*)(&As[row][c0]) = va;
      *(u32x4*)(&Bs[row][c0]) = vb;
    }
    __syncthreads();
#pragma unroll
    for (int ks = 0; ks < 2; ++ks) {
      s16x8 af[4], bf[4];
#pragma unroll
      for (int m = 0; m < 4; ++m)
        af[m] = *(const s16x8*)(&As[wm * 64 + m * 16 + (lane & 15)][ks * 32 + (lane >> 4) * 8]);
#pragma unroll
      for (int n = 0; n < 4; ++n)
        bf[n] = *(const s16x8*)(&Bs[wn * 64 + n * 16 + (lane & 15)][ks * 32 + (lane >> 4) * 8]);
#pragma unroll
      for (int m = 0; m < 4; ++m)
#pragma unroll
        for (int n = 0; n < 4; ++n)
          acc[m][n] = __builtin_amdgcn_mfma_f32_16x16x32_bf16(af[m], bf[n], acc[m][n], 0, 0, 0);
    }
  }
#pragma unroll
  for (int n = 0; n < 4; ++n) {
    int col = n0 + wn * 64 + n * 16 + (lane & 15);
    float bv = bias[col];
#pragma unroll
    for (int m = 0; m < 4; ++m) {
      int rowb = m0 + wm * 64 + m * 16 + (lane >> 4) * 4;
#pragma unroll
      for (int r = 0; r < 4; ++r)
        C[(size_t)(rowb + r) * NV + col] = acc[m][n][r] + bv;
    }
  }
}

// ---------------- host launch ----------------

extern "C" void kernel_launch(void* const* d_in, const int* in_sizes, int n_in,
                              void* d_out, int out_size, void* d_ws, size_t ws_size,
                              hipStream_t stream) {
  const int*   x    = (const int*)d_in[0];
  const float* enc  = (const float*)d_in[1];
  const float* efs  = (const float*)d_in[2];
  const float* emb  = (const float*)d_in[3];
  const float* epw  = (const float*)d_in[4];
  const float* epb  = (const float*)d_in[5];
  const float* wq   = (const float*)d_in[6];
  const float* wk   = (const float*)d_in[7];
  const float* wv   = (const float*)d_in[8];
  const float* wih0 = (const float*)d_in[9];
  const float* whh0 = (const float*)d_in[10];
  const float* bih0 = (const float*)d_in[11];
  const float* bhh0 = (const float*)d_in[12];
  const float* wih1 = (const float*)d_in[13];
  const float* whh1 = (const float*)d_in[14];
  const float* bih1 = (const float*)d_in[15];
  const float* bhh1 = (const float*)d_in[16];
  const float* dw   = (const float*)d_in[17];
  const float* db   = (const float*)d_in[18];

  // workspace layout (bytes). The 16.38MB dwbf16 region is aliased during setup/scan by:
  //   wq16, wk16, wih0T, whh0T, wih1T, whh1T, kvL — all dead before conv_bf16 runs.
  const size_t o_alias  = 0;                            // 16,384,000
  const size_t a_wq16   = 0;                            // 131,072
  const size_t a_wk16   = a_wq16 + 131072;              // 131,072
  const size_t a_wih0T  = a_wk16 + 131072;              // 786,432
  const size_t a_whh0T  = a_wih0T + 786432;             // 393,216
  const size_t a_wih1T  = a_whh0T + 393216;             // 393,216
  const size_t a_whh1T  = a_wih1T + 393216;             // 393,216
  const size_t a_kvL    = a_whh1T + 393216;             // 8,388,608  (ends at 10,616,832)
  const size_t o_wT     = o_alias + 16384000;           // 524,288
  const size_t o_kprojL = o_wT + 524288;                // 8,388,608
  const size_t o_outs   = o_kprojL + 8388608;           // 4,194,304
  const size_t o_spart  = o_outs + 4194304;             // 524,288
  const size_t o_vec0   = o_spart + 524288;             // 1,048,576
  const size_t o_vec1   = o_vec0 + 1048576;             // 1,048,576
  const size_t o_bar    = o_vec1 + 1048576;             // 4,096
  const size_t need     = o_bar + 4096;                 // ~32.1 MB
  if (ws_size < need) return;  // fail visibly rather than corrupt

  char* ws = (char*)d_ws;
  unsigned short* dwbf16 = (unsigned short*)(ws + o_alias);
  _Float16* wq16     = (_Float16*)(ws + a_wq16);
  _Float16* wk16     = (_Float16*)(ws + a_wk16);
  unsigned int* wih0T = (unsigned int*)(ws + a_wih0T);
  unsigned int* whh0T = (unsigned int*)(ws + a_whh0T);
  unsigned int* wih1T = (unsigned int*)(ws + a_wih1T);
  unsigned int* whh1T = (unsigned int*)(ws + a_whh1T);
  _Float16* kvL      = (_Float16*)(ws + a_kvL);
  float* wT          = (float*)(ws + o_wT);
  _Float16* kprojL   = (_Float16*)(ws + o_kprojL);
  unsigned short* outs_bf = (unsigned short*)(ws + o_outs);
  float* spart       = (float*)(ws + o_spart);
  float* vec0        = (float*)(ws + o_vec0);
  float* vec1        = (float*)(ws + o_vec1);
  int* bars          = (int*)(ws + o_bar);

  float* logits = (float*)d_out;
  float* attn_out = logits + (size_t)NB * NT * NV;

  hipMemsetAsync(ws + o_bar, 0, 4096, stream);

  // weight prep
  conv_f16_kernel<<<(65536 + 255) / 256, 256, 0, stream>>>(wq, wq16, 65536);
  conv_f16_kernel<<<(65536 + 255) / 256, 256, 0, stream>>>(wk, wk16, 65536);
  packT_kernel<<<(768 * 256 + 255) / 256, 256, 0, stream>>>(wih0, wih0T, 768, 512);
  packT_kernel<<<(768 * 128 + 255) / 256, 256, 0, stream>>>(whh0, whh0T, 768, 256);
  packT_kernel<<<(768 * 128 + 255) / 256, 256, 0, stream>>>(wih1, wih1T, 768, 256);
  packT_kernel<<<(768 * 128 + 255) / 256, 256, 0, stream>>>(whh1, whh1T, 768, 256);
  transpose_kernel<<<(131072 + 255) / 256, 256, 0, stream>>>(epw, wT);

  // encoder projection -> kvL[b][l][h] (f16), then key projections -> kprojL[b][l][g] (f16)
  proj_kernel<<<(NTP1 * NB * 64) / 256, 256, 0, stream>>>(enc, wT, epb, kvL);
  kproj0_kernel<<<NB * 8, 256, 0, stream>>>(kvL, wk, kprojL);

  // cooperative scan: 256 WGs (8 per batch), 512 threads each — 1 WG/CU co-resident
  scan_kernel<<<256, 512, 0, stream>>>(x, efs, emb, wv, bih0, bhh0, bih1, bhh1,
                                       wq16, wk16, wih0T, whh0T, wih1T, whh1T,
                                       (const unsigned int*)kvL, (const unsigned int*)kprojL,
                                       spart, vec0, vec1, bars,
                                       outs_bf, attn_out);

  // now safe to overwrite the alias region with bf16 dense_w
  conv_bf16_kernel<<<(8192000 + 255) / 256, 256, 0, stream>>>(dw, dwbf16, 8192000);

  // final big GEMM: logits
  logits_gemm<<<(NB * NT / 128) * (NV / 128), 256, 0, stream>>>(outs_bf, dwbf16, db, logits);
}